// Round 25
// baseline (2599.307 us; speedup 1.0000x reference)
//
#include <hip/hip_runtime.h>
#include <stdint.h>

// ---------------------------------------------------------------------------
// QuantumOlfactoryReceptor: full pipeline
// Round 25: base = R24 (2544us best). Hide remaining serial copies/reductions:
//  (1) NCH double-buffered; noise chunk staging fused as light copy branches:
//      chunks 0,1 into k_qb (under quantum), chunks 2,3,4 into k_fused
//      slots 0-2 (blocks 1408-3455, writing the alternate NCH buffer).
//      All 5 standalone k_noiseconv launches removed.
//  (2) Tail: k_tail = cffill || val || ent (block ranges); k_consfin =
//      cons + entfin. 8 tail launches -> 5.
// ---------------------------------------------------------------------------

using short8 = __attribute__((ext_vector_type(8))) short;
using f32x4  = __attribute__((ext_vector_type(4))) float;

#define DEV static __device__ __forceinline__

typedef const __attribute__((address_space(1))) void GV;
typedef __attribute__((address_space(3))) void LV;
DEV void gload16(const void* g, void* l) {
  __builtin_amdgcn_global_load_lds((GV*)g, (LV*)l, 16, 0, 0);
}

DEV ushort f2b(float x) {                       // f32 -> bf16 RNE
  union { float f; uint32_t u; } v; v.f = x;
  uint32_t r = v.u + 0x7FFFu + ((v.u >> 16) & 1u);
  return (ushort)(r >> 16);
}
DEV float b2f(ushort x) {
  union { uint32_t u; float f; } v; v.u = ((uint32_t)x) << 16; return v.f;
}
DEV float sigf(float x) { return 1.f / (1.f + __expf(-x)); }
DEV float tanh_fast(float x) {
  float xc = fminf(9.f, fmaxf(-9.f, x));
  float e = __expf(2.f * xc);
  return (e - 1.f) / (e + 1.f);
}

// noise chunk copy body: 10 timesteps starting at t0 -> dst [10*2048][448] bf16
DEV void noisecopy(const float* __restrict__ noise, ushort* __restrict__ dst,
                   int t0, long start, long stride) {
  const long n = 10L * 2048 * 448;
  for (long idx = start; idx < n; idx += stride) {
    int r = (int)(idx % 448);
    long row = idx / 448;
    int b = (int)(row & 2047);
    int tl = (int)(row >> 11);
    ushort v = 0;
    if (r < 400)
      v = f2b(__builtin_nontemporal_load(&noise[((long)b * 50 + t0 + tl) * 400 + r]));
    dst[idx] = v;
  }
}

// ---------------------------------------------------------------------------
// batched fp32->bf16 weight conversion: 13 jobs, 256 blocks each.
// ---------------------------------------------------------------------------
struct CJob { const float* src; ushort* dst; const float* scale;
              long n; int sr, sc, dc, mode; };
struct CJobs { CJob j[13]; };

__global__ __launch_bounds__(256)
void k_convbatch(CJobs jobs) {
  const int job = blockIdx.x >> 8;
  const int blk = blockIdx.x & 255;
  const CJob J = jobs.j[job];
  for (long idx = (long)blk * 256 + threadIdx.x; idx < J.n; idx += 256L * 256) {
    int r = (int)(idx / J.dc), c = (int)(idx % J.dc);
    float v = 0.f;
    if (r < J.sr && c < J.sc) {
      v = J.src[(long)r * J.sc + c];
      if (J.mode == 1) v *= sigf(J.scale[c]);
    }
    J.dst[idx] = f2b(v);
  }
}

__global__ __launch_bounds__(256)
void k_vadd3(const float* a0, const float* b0, const float* a1, const float* b1,
             const float* a2, const float* b2, float* o) {
  const int job = blockIdx.x >> 2;
  const int i = (blockIdx.x & 3) * 256 + threadIdx.x;
  const float* a = (job == 0) ? a0 : (job == 1) ? a1 : a2;
  const float* b = (job == 0) ? b0 : (job == 1) ? b1 : b2;
  o[job * 1024 + i] = a[i] + b[i];
}

// ---------------------------------------------------------------------------
// FUSED quantum || biofill || noise chunks 0,1. Blocks 0-255: quantum.
// Blocks 256-2303: biofill. Blocks 2304-6399: chunk0->nch0. 6400-10495: ch1.
// ---------------------------------------------------------------------------
__global__ __launch_bounds__(256)
void k_qb(const float* __restrict__ ampr_in, const float* __restrict__ ampi_in,
          const float* __restrict__ Hre, const float* __restrict__ Him,
          const float* __restrict__ mf, ushort* __restrict__ bio,
          float* __restrict__ ampr_out, float* __restrict__ ampi_out,
          const float* __restrict__ noise,
          ushort* __restrict__ nch0, ushort* __restrict__ nch1) {
  const int tid = threadIdx.x;
  if (blockIdx.x < 256) {
    const int gid = blockIdx.x * 256 + tid;
    const int b = gid >> 5;          // sample
    const int l32 = gid & 31;
    const int i = l32 & 15;          // row
    const int h = l32 >> 4;          // column half
    float hre[8], him[8];
#pragma unroll
    for (int jj = 0; jj < 8; jj++) {
      hre[jj] = Hre[i * 16 + h * 8 + jj];
      him[jj] = Him[i * 16 + h * 8 + jj];
    }
    const float mfi = mf[(long)b * 512 + i];
    float are = ampr_in[b * 16 + i], aim = ampi_in[b * 16 + i];
    float ss = are * are + aim * aim;
#pragma unroll
    for (int m = 1; m < 32; m <<= 1) ss += __shfl_xor(ss, m, 32);
    ss *= 0.5f;
    const float inv = 1.f / sqrtf(ss);
    are *= inv; aim *= inv;
#pragma unroll 1
    for (int st = 0; st < 100; ++st) {
      const float t = (float)st * 0.01f;
      const float fac = 1.f + t * mfi;
      const float dec = __expf(-t * 0.02f);   // exp(-t/50)
      float tre = are, tim = aim, rre = are, rim = aim;
#pragma unroll 1
      for (int k = 1; k <= 5; k++) {
        float w1r = 0.f, w1i = 0.f, w2r = 0.f, w2i = 0.f;
#pragma unroll
        for (int jj = 0; jj < 8; jj++) {
          const float vr = __shfl(tre, h * 8 + jj, 32);
          const float vi = __shfl(tim, h * 8 + jj, 32);
          w1r += hre[jj] * vr; w1i += hre[jj] * vi;
          w2r += him[jj] * vr; w2i += him[jj] * vi;
        }
        w1r += __shfl_xor(w1r, 16, 32);
        w1i += __shfl_xor(w1i, 16, 32);
        w2r += __shfl_xor(w2r, 16, 32);
        w2i += __shfl_xor(w2i, 16, 32);
        const float hr = w1r * fac - w2i;      // (Ht v)_re
        const float hi = w1i * fac + w2r;      // (Ht v)_im
        const float sk = 0.01f / (float)k;     // DT/k ; term *= -i*sk
        tre = sk * hi; tim = -sk * hr;
        rre += tre; rim += tim;
      }
      are = rre * dec; aim = rim * dec;
    }
    if (h == 0) {
      ampr_out[b * 16 + i] = are;
      ampi_out[b * 16 + i] = aim;
      bio[(long)b * 576 + i] = f2b(are * are + aim * aim);   // obs
    }
  } else if (blockIdx.x < 2304) {
    for (long i = (long)(blockIdx.x - 256) * 256 + tid; i < (long)2048 * 512;
         i += 2048L * 256) {
      long b = i >> 9, k = i & 511;
      bio[b * 576 + 16 + k] = f2b(mf[i]);
    }
  } else {
    const int cr = blockIdx.x - 2304;       // 0..8191
    const int half = cr >> 12;              // 0 or 1
    const int blk = cr & 4095;
    noisecopy(noise, half ? nch1 : nch0, half * 10,
              (long)blk * 256 + tid, 4096L * 256);
  }
}

// ---------------------------------------------------------------------------
// bf16 MFMA GEMM (standalone, 256 thr / 4 waves): used for small tiles.
// ---------------------------------------------------------------------------
template<int BT>
__global__ __launch_bounds__(256)
void k_gemm(const ushort* __restrict__ A, int lda,
            const ushort* __restrict__ W, int ldw,
            const float* __restrict__ bias,
            const ushort* __restrict__ Gg, int t0,
            float* __restrict__ Cf, int ldcf,
            ushort* __restrict__ Cb, int ldcb,
            int N, int K, int act, int swz) {
  constexpr int FR = BT / 32;
  constexpr int CH = BT / 32;
  __shared__ __align__(16) ushort lsA[2][BT * 64];
  __shared__ __align__(16) ushort lsB[2][BT * 64];
  const int tid = threadIdx.x;
  const int lane = tid & 63, w = tid >> 6;
  const int lr = lane & 15, lq = lane >> 4;
  const int wm = (w >> 1) * (BT / 2), wn = (w & 1) * (BT / 2);
  int bxb = blockIdx.x, byb = blockIdx.y;
  if (swz) {                      // b-aligned XCD remap (grid 8 x 16T)
    const int id = byb * gridDim.x + bxb;
    const int xcd = id & 7, q = id >> 3;
    byb = (q >> 4) * 16 + xcd * 2 + (q & 1);
    bxb = (q >> 1) & 7;
  }
  const int bm = byb * BT, bn = bxb * BT;
  const int srow = lane >> 3;
  const int scol = (((lane & 7) ^ srow)) * 8;

  auto stage = [&](int buf, int kk) {
#pragma unroll
    for (int c = 0; c < CH; c++) {
      const int ch = w * CH + c;
      const int r = ch * 8 + srow;
      gload16(A + (size_t)(bm + r) * lda + kk + scol, lsA[buf] + ch * 512);
      gload16(W + (size_t)(bn + r) * ldw + kk + scol, lsB[buf] + ch * 512);
    }
  };

  f32x4 acc[FR][FR];
#pragma unroll
  for (int i = 0; i < FR; i++)
#pragma unroll
    for (int j = 0; j < FR; j++) acc[i][j] = (f32x4){0.f, 0.f, 0.f, 0.f};

  stage(0, 0);
  __syncthreads();
  const int T = K >> 6;
  for (int t = 0; t < T; t++) {
    const int cur = t & 1;
    if (t + 1 < T) stage(cur ^ 1, (t + 1) * 64);
    short8 af[FR][2], bf[FR][2];
#pragma unroll
    for (int mi = 0; mi < FR; mi++)
#pragma unroll
      for (int k2 = 0; k2 < 2; k2++) {
        const int row = wm + mi * 16 + lr;
        af[mi][k2] = *(const short8*)(lsA[cur] + (row >> 3) * 512 + (row & 7) * 64 +
                                      (((k2 * 4 + lq) ^ (row & 7)) * 8));
      }
#pragma unroll
    for (int ni = 0; ni < FR; ni++)
#pragma unroll
      for (int k2 = 0; k2 < 2; k2++) {
        const int row = wn + ni * 16 + lr;
        bf[ni][k2] = *(const short8*)(lsB[cur] + (row >> 3) * 512 + (row & 7) * 64 +
                                      (((k2 * 4 + lq) ^ (row & 7)) * 8));
      }
#pragma unroll
    for (int k2 = 0; k2 < 2; k2++)
#pragma unroll
      for (int mi = 0; mi < FR; mi++)
#pragma unroll
        for (int ni = 0; ni < FR; ni++)
          acc[mi][ni] = __builtin_amdgcn_mfma_f32_16x16x32_bf16(
              af[mi][k2], bf[ni][k2], acc[mi][ni], 0, 0, 0);
    __syncthreads();
  }

#pragma unroll
  for (int mi = 0; mi < FR; mi++) {
#pragma unroll
    for (int r = 0; r < 4; r++) {
      const int row = bm + wm + mi * 16 + lq * 4 + r;
      float gfac = 0.f; const ushort* ggrow = nullptr;
      if (Gg) {
        gfac = __expf(-(float)(t0 + (row >> 11)) * 0.1f);   // adapt(t)
        ggrow = Gg + (size_t)(row & 2047) * 1024;
      }
#pragma unroll
      for (int ni = 0; ni < FR; ni++) {
        const int col = bn + wn + ni * 16 + lr;
        if (col < N) {
          float v = acc[mi][ni][r];
          if (bias) v += bias[col];
          if (Gg)  v += gfac * b2f(ggrow[col]);
          if (act == 1) v = fmaxf(v, 0.f);
          else if (act == 2) v = tanh_fast(v);
          else if (act == 3) v = sigf(v);
          if (Cf) Cf[(size_t)row * ldcf + col] = v;
          if (Cb) Cb[(size_t)row * ldcb + col] = f2b(v);
        }
      }
    }
  }
}

// ---------------------------------------------------------------------------
// 8-wave standalone BT=128 GEMM (extraction of the fused gemm path) for G[0].
// ---------------------------------------------------------------------------
__global__ __launch_bounds__(512, 2)
void k_gemm8(const ushort* __restrict__ gA, int glda,
             const ushort* __restrict__ gW,
             const float* __restrict__ gbias, const ushort* __restrict__ gGg,
             int gt0, ushort* __restrict__ gC, int gK) {
  __shared__ __align__(16) ushort lsA[2 * 8192];
  __shared__ __align__(16) ushort lsB[2 * 8192];
  const int tid = threadIdx.x;
  const int gb = blockIdx.x;             // 0..1279 = 8 x 160
  const int xcd = gb & 7, q = gb >> 3;
  const int byb = (q >> 4) * 16 + xcd * 2 + (q & 1);
  const int bxb = (q >> 1) & 7;
  const int bm = byb * 128, bn = bxb * 128;
  const int lane = tid & 63, wg = tid >> 6;     // wg in [0,8)
  const int lr = lane & 15, lq = lane >> 4;
  const int wm = (wg >> 2) * 64, wn = (wg & 3) * 32;
  const int srow = lane >> 3;
  const int scol = (((lane & 7) ^ srow)) * 8;

  f32x4 acc[4][2];
#pragma unroll
  for (int i = 0; i < 4; i++)
#pragma unroll
    for (int j = 0; j < 2; j++) acc[i][j] = (f32x4){0.f, 0.f, 0.f, 0.f};

#pragma unroll
  for (int c = 0; c < 2; c++) {
    const int ch = wg * 2 + c;
    const int r = ch * 8 + srow;
    gload16(gA + (size_t)(bm + r) * glda + scol, lsA + ch * 512);
    gload16(gW + (size_t)(bn + r) * glda + scol, lsB + ch * 512);
  }
  __syncthreads();

  const int T = gK >> 6;
  for (int t = 0; t < T; t++) {
    const int cur = t & 1;
    if (t + 1 < T) {
      const int kk = (t + 1) * 64;
#pragma unroll
      for (int c = 0; c < 2; c++) {
        const int ch = wg * 2 + c;
        const int r = ch * 8 + srow;
        gload16(gA + (size_t)(bm + r) * glda + kk + scol, lsA + (cur ^ 1) * 8192 + ch * 512);
        gload16(gW + (size_t)(bn + r) * glda + kk + scol, lsB + (cur ^ 1) * 8192 + ch * 512);
      }
    }
    {
      short8 af[4][2], bf[2][2];
#pragma unroll
      for (int mi = 0; mi < 4; mi++)
#pragma unroll
        for (int k2 = 0; k2 < 2; k2++) {
          const int row = wm + mi * 16 + lr;
          af[mi][k2] = *(const short8*)(lsA + cur * 8192 + (row >> 3) * 512 +
                                        (row & 7) * 64 + (((k2 * 4 + lq) ^ (row & 7)) * 8));
        }
#pragma unroll
      for (int ni = 0; ni < 2; ni++)
#pragma unroll
        for (int k2 = 0; k2 < 2; k2++) {
          const int row = wn + ni * 16 + lr;
          bf[ni][k2] = *(const short8*)(lsB + cur * 8192 + (row >> 3) * 512 +
                                        (row & 7) * 64 + (((k2 * 4 + lq) ^ (row & 7)) * 8));
        }
#pragma unroll
      for (int k2 = 0; k2 < 2; k2++)
#pragma unroll
        for (int mi = 0; mi < 4; mi++)
#pragma unroll
          for (int ni = 0; ni < 2; ni++)
            acc[mi][ni] = __builtin_amdgcn_mfma_f32_16x16x32_bf16(
                af[mi][k2], bf[ni][k2], acc[mi][ni], 0, 0, 0);
    }
    __syncthreads();
  }

#pragma unroll
  for (int mi = 0; mi < 4; mi++) {
#pragma unroll
    for (int r = 0; r < 4; r++) {
      const int row = bm + wm + mi * 16 + lq * 4 + r;
      float gfac = 0.f; const ushort* ggrow = nullptr;
      if (gGg) {
        gfac = __expf(-(float)(gt0 + (row >> 11)) * 0.1f);
        ggrow = gGg + (size_t)(row & 2047) * 1024;
      }
#pragma unroll
      for (int ni = 0; ni < 2; ni++) {
        const int col = bn + wn + ni * 16 + lr;
        float v = acc[mi][ni][r];
        if (gbias) v += gbias[col];
        if (gGg)  v += gfac * b2f(ggrow[col]);
        gC[(size_t)row * 1024 + col] = f2b(v);
      }
    }
  }
}

// ---------------------------------------------------------------------------
// FUSED kernel: blocks 0-127 = LSTM rec; blocks 128-1407 = next job's IH GEMM
// (8 waves, 64x32/wave); blocks 1408-3455 (when ncdst): noise chunk copy.
// ---------------------------------------------------------------------------
__global__ __launch_bounds__(512, 2)
void k_fused(const ushort* __restrict__ IH, const ushort* __restrict__ Whh,
             float* __restrict__ hstate, float* __restrict__ cstate,
             ushort* __restrict__ Hout, float* __restrict__ Xout, int t0,
             const ushort* __restrict__ gA, int glda,
             const ushort* __restrict__ gW,
             const float* __restrict__ gbias, const ushort* __restrict__ gGg,
             int gt0, ushort* __restrict__ gC, int gK,
             const float* __restrict__ noise, ushort* __restrict__ ncdst,
             int nct0) {
  __shared__ __align__(16) ushort upool[37024];   // 74048 B
  const int tid = threadIdx.x;

  if (blockIdx.x < 128) {
    // ================= rec path =================
    ushort (*h_lds)[266] = (ushort(*)[266])upool;        // 4256 ushorts
    ushort* ih0 = upool + 4256;                          // 2 x 16384
    const int lane = tid & 63, w8 = tid >> 6;
    const int lr = lane & 15, lq = lane >> 4;
    const int b0 = blockIdx.x * 16;
    const int wcols = w8 * 32;

    short8 wres[2][8];
#pragma unroll
    for (int cg = 0; cg < 2; cg++) {
      const ushort* wp = Whh + (size_t)(wcols + cg * 16 + lr) * 256 + lq * 8;
#pragma unroll
      for (int kk = 0; kk < 8; kk++) wres[cg][kk] = *(const short8*)(wp + kk * 32);
    }

    float c_reg[2][4], h_reg[2][4];
#pragma unroll
    for (int cg = 0; cg < 2; cg++) {
      const int j = wcols + cg * 16 + lr;
#pragma unroll
      for (int r = 0; r < 4; r++) {
        const int s = lq * 4 + r;
        float hv = hstate[(size_t)(b0 + s) * 256 + j];
        c_reg[cg][r] = cstate[(size_t)(b0 + s) * 256 + j];
        h_reg[cg][r] = hv;
        h_lds[s][j] = f2b(hv);
      }
    }
    __syncthreads();

#define LOADB(buf, g, cg) { \
  const ushort* wp_ = Whh + (size_t)((g) * 256 + wcols + (cg) * 16 + lr) * 256 + lq * 8; \
  _Pragma("unroll") for (int kk = 0; kk < 8; kk++) (buf)[kk] = *(const short8*)(wp_ + kk * 32); }
#define MFMAB(buf, g, cg) { \
  _Pragma("unroll") for (int kk = 0; kk < 8; kk++) \
    acc[cg][g] = __builtin_amdgcn_mfma_f32_16x16x32_bf16(af[kk], (buf)[kk], acc[cg][g], 0, 0, 0); }
#define MFMAR(cg) { \
  _Pragma("unroll") for (int kk = 0; kk < 8; kk++) \
    acc[cg][0] = __builtin_amdgcn_mfma_f32_16x16x32_bf16(af[kk], wres[cg][kk], acc[cg][0], 0, 0, 0); }

    for (int blk = 0; blk < 10; blk += 2) {
      // burst-stage 2 steps of IH (2 x 32 KB) via global_load_lds
#pragma unroll
      for (int si = 0; si < 2; si++) {
        const ushort* src = IH + ((size_t)(blk + si) * 2048 + b0) * 1024;
#pragma unroll
        for (int u = 0; u < 4; u++) {
          const int bi = u * 8 + w8;
          gload16(src + (size_t)bi * 512 + lane * 8, ih0 + si * 16384 + bi * 512);
        }
      }
      __syncthreads();   // stage drained; h_lds from prev step visible

      for (int i2 = 0; i2 < 2; i2++) {
        const int tl = blk + i2;
        const ushort* ihc = ih0 + i2 * 16384;
        short8 af[8];
#pragma unroll
        for (int kk = 0; kk < 8; kk++)
          af[kk] = *(const short8*)(&h_lds[lr][kk * 32 + lq * 8]);
        __syncthreads();   // barrier-A

        f32x4 acc[2][4];
#pragma unroll
        for (int cg = 0; cg < 2; cg++)
#pragma unroll
          for (int g = 0; g < 4; g++) acc[cg][g] = (f32x4){0.f, 0.f, 0.f, 0.f};

        short8 wb0[8], wb1[8];
        LOADB(wb0, 1, 0);
        LOADB(wb1, 1, 1);
        MFMAR(0);
        MFMAR(1);
        MFMAB(wb0, 1, 0);
        LOADB(wb0, 2, 0);
        MFMAB(wb1, 1, 1);
        LOADB(wb1, 2, 1);
        MFMAB(wb0, 2, 0);
        LOADB(wb0, 3, 0);
        MFMAB(wb1, 2, 1);
        LOADB(wb1, 3, 1);
        MFMAB(wb0, 3, 0);
        MFMAB(wb1, 3, 1);

        const int t = t0 + tl;
#pragma unroll
        for (int cg = 0; cg < 2; cg++) {
          const int j = wcols + cg * 16 + lr;
#pragma unroll
          for (int r = 0; r < 4; r++) {
            const int s = lq * 4 + r;
            const float zi = acc[cg][0][r] + b2f(ihc[s * 1024 + j]);
            const float zf = acc[cg][1][r] + b2f(ihc[s * 1024 + 256 + j]);
            const float zg = acc[cg][2][r] + b2f(ihc[s * 1024 + 512 + j]);
            const float zo = acc[cg][3][r] + b2f(ihc[s * 1024 + 768 + j]);
            const float ig = sigf(zi), fg = sigf(zf), gg = tanh_fast(zg), og = sigf(zo);
            const float c = fg * c_reg[cg][r] + ig * gg;
            c_reg[cg][r] = c;
            const float h = og * tanh_fast(c);
            h_reg[cg][r] = h;
            h_lds[s][j] = f2b(h);
            if (Hout) Hout[((size_t)t * 2048 + b0 + s) * 256 + j] = f2b(h);
            if (Xout)
              __builtin_nontemporal_store(h, &Xout[((size_t)(b0 + s) * 50 + t) * 256 + j]);
          }
        }
        __syncthreads();   // barrier-B
      }
    }
#undef LOADB
#undef MFMAB
#undef MFMAR
#pragma unroll
    for (int cg = 0; cg < 2; cg++) {
      const int j = wcols + cg * 16 + lr;
#pragma unroll
      for (int r = 0; r < 4; r++) {
        const int s = lq * 4 + r;
        hstate[(size_t)(b0 + s) * 256 + j] = h_reg[cg][r];
        cstate[(size_t)(b0 + s) * 256 + j] = c_reg[cg][r];
      }
    }
  } else if (blockIdx.x < 1408) {
    // ============ gemm path: ALL 8 waves, 64x32 sub-tile per wave ============
    ushort* lsA = upool;            // 2 x 8192
    ushort* lsB = upool + 16384;    // 2 x 8192
    const int gb = blockIdx.x - 128;       // 0..1279 = 8 x 160
    const int xcd = gb & 7, q = gb >> 3;
    const int byb = (q >> 4) * 16 + xcd * 2 + (q & 1);
    const int bxb = (q >> 1) & 7;
    const int bm = byb * 128, bn = bxb * 128;
    const int lane = tid & 63, wg = tid >> 6;     // wg in [0,8)
    const int lr = lane & 15, lq = lane >> 4;
    const int wm = (wg >> 2) * 64, wn = (wg & 3) * 32;
    const int srow = lane >> 3;
    const int scol = (((lane & 7) ^ srow)) * 8;

    f32x4 acc[4][2];
#pragma unroll
    for (int i = 0; i < 4; i++)
#pragma unroll
      for (int j = 0; j < 2; j++) acc[i][j] = (f32x4){0.f, 0.f, 0.f, 0.f};

#pragma unroll
    for (int c = 0; c < 2; c++) {
      const int ch = wg * 2 + c;
      const int r = ch * 8 + srow;
      gload16(gA + (size_t)(bm + r) * glda + scol, lsA + ch * 512);
      gload16(gW + (size_t)(bn + r) * glda + scol, lsB + ch * 512);
    }
    __syncthreads();

    const int T = gK >> 6;
    for (int t = 0; t < T; t++) {
      const int cur = t & 1;
      if (t + 1 < T) {
        const int kk = (t + 1) * 64;
#pragma unroll
        for (int c = 0; c < 2; c++) {
          const int ch = wg * 2 + c;
          const int r = ch * 8 + srow;
          gload16(gA + (size_t)(bm + r) * glda + kk + scol, lsA + (cur ^ 1) * 8192 + ch * 512);
          gload16(gW + (size_t)(bn + r) * glda + kk + scol, lsB + (cur ^ 1) * 8192 + ch * 512);
        }
      }
      {
        short8 af[4][2], bf[2][2];
#pragma unroll
        for (int mi = 0; mi < 4; mi++)
#pragma unroll
          for (int k2 = 0; k2 < 2; k2++) {
            const int row = wm + mi * 16 + lr;
            af[mi][k2] = *(const short8*)(lsA + cur * 8192 + (row >> 3) * 512 +
                                          (row & 7) * 64 + (((k2 * 4 + lq) ^ (row & 7)) * 8));
          }
#pragma unroll
        for (int ni = 0; ni < 2; ni++)
#pragma unroll
          for (int k2 = 0; k2 < 2; k2++) {
            const int row = wn + ni * 16 + lr;
            bf[ni][k2] = *(const short8*)(lsB + cur * 8192 + (row >> 3) * 512 +
                                          (row & 7) * 64 + (((k2 * 4 + lq) ^ (row & 7)) * 8));
          }
#pragma unroll
        for (int k2 = 0; k2 < 2; k2++)
#pragma unroll
          for (int mi = 0; mi < 4; mi++)
#pragma unroll
            for (int ni = 0; ni < 2; ni++)
              acc[mi][ni] = __builtin_amdgcn_mfma_f32_16x16x32_bf16(
                  af[mi][k2], bf[ni][k2], acc[mi][ni], 0, 0, 0);
      }
      __syncthreads();
    }

    {
#pragma unroll
      for (int mi = 0; mi < 4; mi++) {
#pragma unroll
        for (int r = 0; r < 4; r++) {
          const int row = bm + wm + mi * 16 + lq * 4 + r;
          float gfac = 0.f; const ushort* ggrow = nullptr;
          if (gGg) {
            gfac = __expf(-(float)(gt0 + (row >> 11)) * 0.1f);
            ggrow = gGg + (size_t)(row & 2047) * 1024;
          }
#pragma unroll
          for (int ni = 0; ni < 2; ni++) {
            const int col = bn + wn + ni * 16 + lr;
            float v = acc[mi][ni][r];
            if (gbias) v += gbias[col];
            if (gGg)  v += gfac * b2f(ggrow[col]);
            gC[(size_t)row * 1024 + col] = f2b(v);
          }
        }
      }
    }
  } else {
    // ============ noise chunk copy (slots 0-2 only) ============
    const int blk = blockIdx.x - 1408;     // 0..2047
    noisecopy(noise, ncdst, nct0, (long)blk * 512 + tid, 2048L * 512);
  }
}

// ---------------------------------------------------------------------------
// TAIL: blocks 0-5255 cffill; 5256-7303 valence; 7304-7311 entropy (8x256).
// ---------------------------------------------------------------------------
__global__ __launch_bounds__(256)
void k_tail(const float* __restrict__ hT, const ushort* __restrict__ recb,
            ushort* __restrict__ cf,
            const float* __restrict__ x, float* __restrict__ valout,
            const float* __restrict__ ar, const float* __restrict__ ai,
            float* __restrict__ partial) {
  __shared__ float red[256];
  const int tid = threadIdx.x;
  if (blockIdx.x < 5256) {
    long i = (long)blockIdx.x * 256 + tid;
    if (i < (long)2048 * 656) {
      long b = i / 656; int c = (int)(i % 656);
      cf[b * 704 + c] = (c < 256) ? f2b(hT[b * 256 + c]) : recb[b * 448 + (c - 256)];
    }
  } else if (blockIdx.x < 7304) {
    const float* p = x + (size_t)(blockIdx.x - 5256) * 12800;
    float a = 0.f;
    for (int i = tid; i < 12800; i += 256) a += tanh_fast(p[i]);
    red[tid] = a; __syncthreads();
    for (int s = 128; s > 0; s >>= 1) {
      if (tid < s) red[tid] += red[tid + s];
      __syncthreads();
    }
    if (tid == 0) valout[blockIdx.x - 5256] = red[0] * (1.f / 12800.f);
  } else {
    const int b = (blockIdx.x - 7304) * 256 + tid;
    float vr[16], vi[16];
#pragma unroll
    for (int i = 0; i < 16; i++) { vr[i] = ar[b * 16 + i]; vi[i] = ai[b * 16 + i]; }
    float m[64];
#pragma unroll
    for (int j = 0; j < 4; j++)
#pragma unroll
      for (int k = 0; k < 4; k++) {
        float re = 0.f, im = 0.f;
#pragma unroll
        for (int i = 0; i < 4; i++) {
          float xr = vr[i * 4 + j], xi = vi[i * 4 + j];
          float yr = vr[i * 4 + k], yi = vi[i * 4 + k];
          re += xr * yr + xi * yi;
          im += xi * yr - xr * yi;
        }
        m[j * 8 + k] = re;
        m[j * 8 + (k + 4)] = -im;
        m[(j + 4) * 8 + k] = im;
        m[(j + 4) * 8 + (k + 4)] = re;
      }
#pragma unroll 1
    for (int sweep = 0; sweep < 6; ++sweep) {
#pragma unroll
      for (int p = 0; p < 7; p++) {
#pragma unroll
        for (int q = p + 1; q < 8; q++) {
          const float apq = m[p * 8 + q];
          if (fabsf(apq) > 1e-28f) {
            const float app = m[p * 8 + p], aqq = m[q * 8 + q];
            const float tau = (aqq - app) / (2.f * apq);
            const float tt = (tau >= 0.f ? 1.f : -1.f) /
                             (fabsf(tau) + sqrtf(1.f + tau * tau));
            const float cc = 1.f / sqrtf(1.f + tt * tt);
            const float ssn = tt * cc;
#pragma unroll
            for (int k2 = 0; k2 < 8; k2++) {
              const float mp = m[p * 8 + k2], mq = m[q * 8 + k2];
              m[p * 8 + k2] = cc * mp - ssn * mq;
              m[q * 8 + k2] = ssn * mp + cc * mq;
            }
#pragma unroll
            for (int k2 = 0; k2 < 8; k2++) {
              const float mp = m[k2 * 8 + p], mq = m[k2 * 8 + q];
              m[k2 * 8 + p] = cc * mp - ssn * mq;
              m[k2 * 8 + q] = ssn * mp + cc * mq;
            }
          }
        }
      }
    }
    float e = 0.f;
#pragma unroll
    for (int k2 = 0; k2 < 8; k2++) {
      const float lam = fmaxf(m[k2 * 8 + k2], 1e-12f);
      e -= lam * logf(lam);
    }
    red[tid] = e; __syncthreads();
    for (int s = 128; s > 0; s >>= 1) {
      if (tid < s) red[tid] += red[tid + s];
      __syncthreads();
    }
    if (tid == 0) partial[blockIdx.x - 7304] = red[0];
  }
}

// block 0: consumer head mean; block 1: entropy finalize.
__global__ __launch_bounds__(256)
void k_consfin(const float* __restrict__ c3, const float* __restrict__ w4,
               const float* __restrict__ b4, float* __restrict__ outc,
               const float* __restrict__ partial, float* __restrict__ oute) {
  if (blockIdx.x == 0) {
    __shared__ float red[256];
    float accv = 0.f;
    for (int b = threadIdx.x; b < 2048; b += 256) {
      float d = b4[0];
#pragma unroll
      for (int k = 0; k < 64; k++) d += c3[(long)b * 64 + k] * w4[k];
      accv += sigf(d);
    }
    red[threadIdx.x] = accv; __syncthreads();
    for (int s = 128; s > 0; s >>= 1) {
      if (threadIdx.x < s) red[threadIdx.x] += red[threadIdx.x + s];
      __syncthreads();
    }
    if (threadIdx.x == 0) outc[0] = red[0] * (1.f / 2048.f);
  } else if (threadIdx.x == 0) {
    float s = 0.f;
    for (int i = 0; i < 8; i++) s += partial[i];
    oute[0] = s * (0.5f / 2048.f);
  }
}

// ---------------------------------------------------------------------------
extern "C" void kernel_launch(void* const* d_in, const int* in_sizes, int n_in,
                              void* d_out, int out_size, void* d_ws, size_t ws_size,
                              hipStream_t stream) {
  (void)in_sizes; (void)n_in; (void)out_size; (void)ws_size;
  const float* mf    = (const float*)d_in[0];
  const float* noise = (const float*)d_in[1];
  const float* ampr  = (const float*)d_in[2];
  const float* ampi  = (const float*)d_in[3];
  const float* Hre   = (const float*)d_in[4];
  const float* Him   = (const float*)d_in[5];
  const float* gpc   = (const float*)d_in[6];
  const float* bw1 = (const float*)d_in[7];  const float* bb1 = (const float*)d_in[8];
  const float* bw2 = (const float*)d_in[9];  const float* bb2 = (const float*)d_in[10];
  const float* bw3 = (const float*)d_in[11]; const float* bb3 = (const float*)d_in[12];
  const float* Wih[3] = {(const float*)d_in[13], (const float*)d_in[17], (const float*)d_in[21]};
  const float* Whh[3] = {(const float*)d_in[14], (const float*)d_in[18], (const float*)d_in[22]};
  const float* bih[3] = {(const float*)d_in[15], (const float*)d_in[19], (const float*)d_in[23]};
  const float* bhh[3] = {(const float*)d_in[16], (const float*)d_in[20], (const float*)d_in[24]};
  const float* cw1 = (const float*)d_in[25]; const float* cb1 = (const float*)d_in[26];
  const float* cw2 = (const float*)d_in[27]; const float* cb2 = (const float*)d_in[28];
  const float* cw3 = (const float*)d_in[29]; const float* cb3 = (const float*)d_in[30];
  const float* cw4 = (const float*)d_in[31]; const float* cb4 = (const float*)d_in[32];

  float* out = (float*)d_out;
  float* out_rec  = out;                    // [2048][400]
  float* out_seq  = out + 819200;           // [2048][50][256]
  float* out_val  = out + 27033600;         // [2048]
  float* out_cons = out + 27035648;
  float* out_ent  = out + 27035649;

  char* ws = (char*)d_ws;
  size_t off = 0;
  auto alloc = [&](size_t bytes) -> char* {
    char* p = ws + off; off += (bytes + 255) & ~(size_t)255; return p;
  };
  ushort* WB1   = (ushort*)alloc((size_t)256 * 576 * 2);
  ushort* WB2   = (ushort*)alloc((size_t)128 * 256 * 2);
  ushort* WB3   = (ushort*)alloc((size_t)512 * 128 * 2);
  ushort* WIH0  = (ushort*)alloc((size_t)1024 * 448 * 2);
  ushort* WIH0S = (ushort*)alloc((size_t)1024 * 448 * 2);
  ushort* WIH1  = (ushort*)alloc((size_t)1024 * 256 * 2);
  ushort* WIH2  = (ushort*)alloc((size_t)1024 * 256 * 2);
  ushort* WHH0  = (ushort*)alloc((size_t)1024 * 256 * 2);
  ushort* WHH1  = (ushort*)alloc((size_t)1024 * 256 * 2);
  ushort* WHH2  = (ushort*)alloc((size_t)1024 * 256 * 2);
  ushort* WC1   = (ushort*)alloc((size_t)512 * 704 * 2);
  ushort* WC2   = (ushort*)alloc((size_t)256 * 512 * 2);
  ushort* WC3   = (ushort*)alloc((size_t)128 * 256 * 2);
  float*  BSUM  = (float*)alloc((size_t)3 * 1024 * 4);
  ushort* BIO   = (ushort*)alloc((size_t)2048 * 576 * 2);
  ushort* H1B   = (ushort*)alloc((size_t)2048 * 256 * 2);
  ushort* H2B   = (ushort*)alloc((size_t)2048 * 128 * 2);
  ushort* RECB  = (ushort*)alloc((size_t)2048 * 448 * 2);
  ushort* GGB   = (ushort*)alloc((size_t)2048 * 1024 * 2);
  float*  AMPR  = (float*)alloc((size_t)2048 * 16 * 4);
  float*  AMPI  = (float*)alloc((size_t)2048 * 16 * 4);
  ushort* NCH0  = (ushort*)alloc((size_t)10 * 2048 * 448 * 2);
  ushort* NCH1  = (ushort*)alloc((size_t)10 * 2048 * 448 * 2);
  ushort* IHCA  = (ushort*)alloc((size_t)10 * 2048 * 1024 * 2);
  ushort* IHCB  = (ushort*)alloc((size_t)10 * 2048 * 1024 * 2);
  ushort* HBUF  = (ushort*)alloc((size_t)50 * 2048 * 256 * 2);
  float*  HST   = (float*)alloc((size_t)2048 * 256 * 4);
  float*  CST   = (float*)alloc((size_t)2048 * 256 * 4);   // adjacent to HST
  ushort* CFB   = (ushort*)alloc((size_t)2048 * 704 * 2);
  ushort* C1B   = (ushort*)alloc((size_t)2048 * 512 * 2);
  ushort* C2B   = (ushort*)alloc((size_t)2048 * 256 * 2);
  float*  C3F   = (float*)alloc((size_t)2048 * 64 * 4);
  float*  ENTP  = (float*)alloc((size_t)8 * 4);

  hipMemsetAsync(BIO,  0, (size_t)2048 * 576 * 2, stream);
  hipMemsetAsync(RECB, 0, (size_t)2048 * 448 * 2, stream);
  hipMemsetAsync(CFB,  0, (size_t)2048 * 704 * 2, stream);

  // ---- batched weight conversions (one launch) ----
  CJobs cj;
  auto J = [&](int k, const float* s, ushort* d, int sr, int dr, int sc, int dc,
               const float* sc_, int mode) {
    cj.j[k] = CJob{s, d, sc_, (long)dr * dc, sr, sc, dc, mode};
  };
  J(0,  bw1,    WB1,   256, 256, 528, 576, nullptr, 0);
  J(1,  bw2,    WB2,   128, 128, 256, 256, nullptr, 0);
  J(2,  bw3,    WB3,   400, 512, 128, 128, nullptr, 0);
  J(3,  Wih[0], WIH0,  1024, 1024, 400, 448, nullptr, 0);
  J(4,  Wih[0], WIH0S, 1024, 1024, 400, 448, gpc, 1);
  J(5,  Wih[1], WIH1,  1024, 1024, 256, 256, nullptr, 0);
  J(6,  Wih[2], WIH2,  1024, 1024, 256, 256, nullptr, 0);
  J(7,  Whh[0], WHH0,  1024, 1024, 256, 256, nullptr, 0);
  J(8,  Whh[1], WHH1,  1024, 1024, 256, 256, nullptr, 0);
  J(9,  Whh[2], WHH2,  1024, 1024, 256, 256, nullptr, 0);
  J(10, cw1,    WC1,   512, 512, 656, 704, nullptr, 0);
  J(11, cw2,    WC2,   256, 256, 512, 512, nullptr, 0);
  J(12, cw3,    WC3,   64, 128, 256, 256, nullptr, 0);
  hipLaunchKernelGGL(k_convbatch, dim3(13 * 256), dim3(256), 0, stream, cj);
  hipLaunchKernelGGL(k_vadd3, dim3(12), dim3(256), 0, stream,
                     bih[0], bhh[0], bih[1], bhh[1], bih[2], bhh[2], BSUM);

  // quantum || biofill || noise chunks 0,1 (one launch)
  hipLaunchKernelGGL(k_qb, dim3(10496), dim3(256), 0, stream,
                     ampr, ampi, Hre, Him, mf, BIO, AMPR, AMPI,
                     noise, NCH0, NCH1);

  auto gemm = [&](bool big, const ushort* A, int lda, const ushort* W, int ldw,
                  const float* bias, const ushort* Gg, int t0, float* Cf, int ldcf,
                  ushort* Cb, int ldcb, int M, int N, int K, int act) {
    if (big) {
      dim3 grid((N + 127) / 128, M / 128);
      const int swz = (grid.x == 8 && (grid.y & 15) == 0) ? 1 : 0;
      hipLaunchKernelGGL(k_gemm<128>, grid, dim3(256), 0, stream,
                         A, lda, W, ldw, bias, Gg, t0, Cf, ldcf, Cb, ldcb, N, K, act, swz);
    } else {
      dim3 grid((N + 63) / 64, M / 64);
      hipLaunchKernelGGL(k_gemm<64>, grid, dim3(256), 0, stream,
                         A, lda, W, ldw, bias, Gg, t0, Cf, ldcf, Cb, ldcb, N, K, act, 0);
    }
  };

  // receptor MLP
  gemm(false, BIO, 576, WB1, 576, bb1, nullptr, 0, nullptr, 0, H1B, 256, 2048, 256, 576, 1);
  gemm(false, H1B, 256, WB2, 256, bb2, nullptr, 0, nullptr, 0, H2B, 128, 2048, 128, 256, 2);
  gemm(false, H2B, 128, WB3, 128, bb3, nullptr, 0, out_rec, 400, RECB, 448, 2048, 400, 128, 3);
  // GGB = (receptor * sigmoid(gpc)) @ Wih0^T   (bf16)
  gemm(false, RECB, 448, WIH0S, 448, nullptr, nullptr, 0, nullptr, 0, GGB, 1024, 2048, 1024, 448, 0);

  // ---- fused LSTM pipeline: slot i = rec job i || gemm job i+1 ----
  const ushort* WHHl[3] = {WHH0, WHH1, WHH2};
  ushort* IHCbuf[2] = {IHCA, IHCB};
  ushort* NCHbuf[2] = {NCH0, NCH1};
  // G[0] standalone (8-wave); NCH0 chunk 0 staged by k_qb
  hipLaunchKernelGGL(k_gemm8, dim3(1280), dim3(512), 0, stream,
                     NCH0, 448, WIH0, BSUM, GGB, 0, IHCA, 448);

  for (int i = 0; i < 15; i++) {
    const int l = i / 5, c = i % 5;
    if (c == 0) hipMemsetAsync(HST, 0, (size_t)2048 * 256 * 4 * 2, stream);  // HST+CST
    const bool hg = (i + 1 < 15);
    const bool hc = (i <= 2);           // fused copy of noise chunk i+2
    const ushort* gA = nullptr; const ushort* gWp = nullptr;
    const float* gb_ = nullptr; const ushort* gGg = nullptr;
    int glda = 256, gK = 256, ggt0 = 0;
    if (hg) {
      const int l2 = (i + 1) / 5, c2 = (i + 1) % 5;
      if (l2 == 0) {
        gA = NCHbuf[(i + 1) & 1]; glda = 448; gK = 448;
        gb_ = BSUM; gGg = GGB; ggt0 = c2 * 10; gWp = WIH0;
      } else {
        gA = HBUF + (size_t)(c2 * 10) * 2048 * 256; glda = 256; gK = 256;
        gb_ = BSUM + l2 * 1024; gGg = nullptr; ggt0 = 0;
        gWp = (l2 == 1 ? WIH1 : WIH2);
      }
    }
    dim3 grid(hg ? (hc ? 3456 : 1408) : 128);
    hipLaunchKernelGGL(k_fused, grid, dim3(512), 0, stream,
                       IHCbuf[i & 1], WHHl[l], HST, CST,
                       (l < 2 ? HBUF : (ushort*)nullptr),
                       (l == 2 ? out_seq : (float*)nullptr), c * 10,
                       gA, glda, gWp, gb_, gGg, ggt0, IHCbuf[(i + 1) & 1], gK,
                       noise, hc ? NCHbuf[i & 1] : (ushort*)nullptr, (i + 2) * 10);
  }

  // tail: cffill || valence || entropy (one launch), then consumer MLP
  hipLaunchKernelGGL(k_tail, dim3(7312), dim3(256), 0, stream,
                     HST, RECB, CFB, out_seq, out_val, AMPR, AMPI, ENTP);
  gemm(false, CFB, 704, WC1, 704, cb1, nullptr, 0, nullptr, 0, C1B, 512, 2048, 512, 704, 1);
  gemm(false, C1B, 512, WC2, 512, cb2, nullptr, 0, nullptr, 0, C2B, 256, 2048, 256, 512, 1);
  gemm(false, C2B, 256, WC3, 256, cb3, nullptr, 0, C3F, 64, nullptr, 0, 2048, 64, 256, 2);
  hipLaunchKernelGGL(k_consfin, dim3(2), dim3(256), 0, stream,
                     C3F, cw4, cb4, out_cons, ENTP, out_ent);
}

// Round 26
// 2526.211 us; speedup vs baseline: 1.0289x; 1.0289x over previous
//
#include <hip/hip_runtime.h>
#include <stdint.h>

// ---------------------------------------------------------------------------
// QuantumOlfactoryReceptor: full pipeline
// Round 26: hybrid of R24 (best=2544) + the non-regressing parts of R25.
//  - k_fused: reverted to R24 (NO noise-copy branch -- R25 showed copy blocks
//    inherit 74KB LDS -> 2 blocks/CU -> +41us/slot).
//  - k_qb keeps noise chunks 0,1 staging (no-LDS kernel, hidden under
//    latency-bound quantum): removes 2 serial noiseconv launches.
//  - tail fusion kept: k_tail = cffill || valence || entropy; k_consfin.
//  - standalone k_noiseconv only for chunks 2,3,4 (slots 1-3), double-buffered.
// ---------------------------------------------------------------------------

using short8 = __attribute__((ext_vector_type(8))) short;
using f32x4  = __attribute__((ext_vector_type(4))) float;

#define DEV static __device__ __forceinline__

typedef const __attribute__((address_space(1))) void GV;
typedef __attribute__((address_space(3))) void LV;
DEV void gload16(const void* g, void* l) {
  __builtin_amdgcn_global_load_lds((GV*)g, (LV*)l, 16, 0, 0);
}

DEV ushort f2b(float x) {                       // f32 -> bf16 RNE
  union { float f; uint32_t u; } v; v.f = x;
  uint32_t r = v.u + 0x7FFFu + ((v.u >> 16) & 1u);
  return (ushort)(r >> 16);
}
DEV float b2f(ushort x) {
  union { uint32_t u; float f; } v; v.u = ((uint32_t)x) << 16; return v.f;
}
DEV float sigf(float x) { return 1.f / (1.f + __expf(-x)); }
DEV float tanh_fast(float x) {
  float xc = fminf(9.f, fmaxf(-9.f, x));
  float e = __expf(2.f * xc);
  return (e - 1.f) / (e + 1.f);
}

// noise chunk copy body: 10 timesteps starting at t0 -> dst [10*2048][448] bf16
DEV void noisecopy(const float* __restrict__ noise, ushort* __restrict__ dst,
                   int t0, long start, long stride) {
  const long n = 10L * 2048 * 448;
  for (long idx = start; idx < n; idx += stride) {
    int r = (int)(idx % 448);
    long row = idx / 448;
    int b = (int)(row & 2047);
    int tl = (int)(row >> 11);
    ushort v = 0;
    if (r < 400)
      v = f2b(__builtin_nontemporal_load(&noise[((long)b * 50 + t0 + tl) * 400 + r]));
    dst[idx] = v;
  }
}

__global__ void k_noiseconv(const float* __restrict__ noise, ushort* __restrict__ dst, int t0) {
  noisecopy(noise, dst, t0, (long)blockIdx.x * blockDim.x + threadIdx.x,
            (long)gridDim.x * blockDim.x);
}

// ---------------------------------------------------------------------------
// batched fp32->bf16 weight conversion: 13 jobs, 256 blocks each.
// ---------------------------------------------------------------------------
struct CJob { const float* src; ushort* dst; const float* scale;
              long n; int sr, sc, dc, mode; };
struct CJobs { CJob j[13]; };

__global__ __launch_bounds__(256)
void k_convbatch(CJobs jobs) {
  const int job = blockIdx.x >> 8;
  const int blk = blockIdx.x & 255;
  const CJob J = jobs.j[job];
  for (long idx = (long)blk * 256 + threadIdx.x; idx < J.n; idx += 256L * 256) {
    int r = (int)(idx / J.dc), c = (int)(idx % J.dc);
    float v = 0.f;
    if (r < J.sr && c < J.sc) {
      v = J.src[(long)r * J.sc + c];
      if (J.mode == 1) v *= sigf(J.scale[c]);
    }
    J.dst[idx] = f2b(v);
  }
}

__global__ __launch_bounds__(256)
void k_vadd3(const float* a0, const float* b0, const float* a1, const float* b1,
             const float* a2, const float* b2, float* o) {
  const int job = blockIdx.x >> 2;
  const int i = (blockIdx.x & 3) * 256 + threadIdx.x;
  const float* a = (job == 0) ? a0 : (job == 1) ? a1 : a2;
  const float* b = (job == 0) ? b0 : (job == 1) ? b1 : b2;
  o[job * 1024 + i] = a[i] + b[i];
}

// ---------------------------------------------------------------------------
// FUSED quantum || biofill || noise chunks 0,1. Blocks 0-255: quantum.
// Blocks 256-2303: biofill. Blocks 2304-6399: chunk0->nch0. 6400-10495: ch1.
// (no LDS here -> copy branches run at full occupancy, hidden under quantum)
// ---------------------------------------------------------------------------
__global__ __launch_bounds__(256)
void k_qb(const float* __restrict__ ampr_in, const float* __restrict__ ampi_in,
          const float* __restrict__ Hre, const float* __restrict__ Him,
          const float* __restrict__ mf, ushort* __restrict__ bio,
          float* __restrict__ ampr_out, float* __restrict__ ampi_out,
          const float* __restrict__ noise,
          ushort* __restrict__ nch0, ushort* __restrict__ nch1) {
  const int tid = threadIdx.x;
  if (blockIdx.x < 256) {
    const int gid = blockIdx.x * 256 + tid;
    const int b = gid >> 5;          // sample
    const int l32 = gid & 31;
    const int i = l32 & 15;          // row
    const int h = l32 >> 4;          // column half
    float hre[8], him[8];
#pragma unroll
    for (int jj = 0; jj < 8; jj++) {
      hre[jj] = Hre[i * 16 + h * 8 + jj];
      him[jj] = Him[i * 16 + h * 8 + jj];
    }
    const float mfi = mf[(long)b * 512 + i];
    float are = ampr_in[b * 16 + i], aim = ampi_in[b * 16 + i];
    float ss = are * are + aim * aim;
#pragma unroll
    for (int m = 1; m < 32; m <<= 1) ss += __shfl_xor(ss, m, 32);
    ss *= 0.5f;
    const float inv = 1.f / sqrtf(ss);
    are *= inv; aim *= inv;
#pragma unroll 1
    for (int st = 0; st < 100; ++st) {
      const float t = (float)st * 0.01f;
      const float fac = 1.f + t * mfi;
      const float dec = __expf(-t * 0.02f);   // exp(-t/50)
      float tre = are, tim = aim, rre = are, rim = aim;
#pragma unroll 1
      for (int k = 1; k <= 5; k++) {
        float w1r = 0.f, w1i = 0.f, w2r = 0.f, w2i = 0.f;
#pragma unroll
        for (int jj = 0; jj < 8; jj++) {
          const float vr = __shfl(tre, h * 8 + jj, 32);
          const float vi = __shfl(tim, h * 8 + jj, 32);
          w1r += hre[jj] * vr; w1i += hre[jj] * vi;
          w2r += him[jj] * vr; w2i += him[jj] * vi;
        }
        w1r += __shfl_xor(w1r, 16, 32);
        w1i += __shfl_xor(w1i, 16, 32);
        w2r += __shfl_xor(w2r, 16, 32);
        w2i += __shfl_xor(w2i, 16, 32);
        const float hr = w1r * fac - w2i;      // (Ht v)_re
        const float hi = w1i * fac + w2r;      // (Ht v)_im
        const float sk = 0.01f / (float)k;     // DT/k ; term *= -i*sk
        tre = sk * hi; tim = -sk * hr;
        rre += tre; rim += tim;
      }
      are = rre * dec; aim = rim * dec;
    }
    if (h == 0) {
      ampr_out[b * 16 + i] = are;
      ampi_out[b * 16 + i] = aim;
      bio[(long)b * 576 + i] = f2b(are * are + aim * aim);   // obs
    }
  } else if (blockIdx.x < 2304) {
    for (long i = (long)(blockIdx.x - 256) * 256 + tid; i < (long)2048 * 512;
         i += 2048L * 256) {
      long b = i >> 9, k = i & 511;
      bio[b * 576 + 16 + k] = f2b(mf[i]);
    }
  } else {
    const int cr = blockIdx.x - 2304;       // 0..8191
    const int half = cr >> 12;              // 0 or 1
    const int blk = cr & 4095;
    noisecopy(noise, half ? nch1 : nch0, half * 10,
              (long)blk * 256 + tid, 4096L * 256);
  }
}

// ---------------------------------------------------------------------------
// bf16 MFMA GEMM (standalone, 256 thr / 4 waves): used for small tiles.
// ---------------------------------------------------------------------------
template<int BT>
__global__ __launch_bounds__(256)
void k_gemm(const ushort* __restrict__ A, int lda,
            const ushort* __restrict__ W, int ldw,
            const float* __restrict__ bias,
            const ushort* __restrict__ Gg, int t0,
            float* __restrict__ Cf, int ldcf,
            ushort* __restrict__ Cb, int ldcb,
            int N, int K, int act, int swz) {
  constexpr int FR = BT / 32;
  constexpr int CH = BT / 32;
  __shared__ __align__(16) ushort lsA[2][BT * 64];
  __shared__ __align__(16) ushort lsB[2][BT * 64];
  const int tid = threadIdx.x;
  const int lane = tid & 63, w = tid >> 6;
  const int lr = lane & 15, lq = lane >> 4;
  const int wm = (w >> 1) * (BT / 2), wn = (w & 1) * (BT / 2);
  int bxb = blockIdx.x, byb = blockIdx.y;
  if (swz) {                      // b-aligned XCD remap (grid 8 x 16T)
    const int id = byb * gridDim.x + bxb;
    const int xcd = id & 7, q = id >> 3;
    byb = (q >> 4) * 16 + xcd * 2 + (q & 1);
    bxb = (q >> 1) & 7;
  }
  const int bm = byb * BT, bn = bxb * BT;
  const int srow = lane >> 3;
  const int scol = (((lane & 7) ^ srow)) * 8;

  auto stage = [&](int buf, int kk) {
#pragma unroll
    for (int c = 0; c < CH; c++) {
      const int ch = w * CH + c;
      const int r = ch * 8 + srow;
      gload16(A + (size_t)(bm + r) * lda + kk + scol, lsA[buf] + ch * 512);
      gload16(W + (size_t)(bn + r) * ldw + kk + scol, lsB[buf] + ch * 512);
    }
  };

  f32x4 acc[FR][FR];
#pragma unroll
  for (int i = 0; i < FR; i++)
#pragma unroll
    for (int j = 0; j < FR; j++) acc[i][j] = (f32x4){0.f, 0.f, 0.f, 0.f};

  stage(0, 0);
  __syncthreads();
  const int T = K >> 6;
  for (int t = 0; t < T; t++) {
    const int cur = t & 1;
    if (t + 1 < T) stage(cur ^ 1, (t + 1) * 64);
    short8 af[FR][2], bf[FR][2];
#pragma unroll
    for (int mi = 0; mi < FR; mi++)
#pragma unroll
      for (int k2 = 0; k2 < 2; k2++) {
        const int row = wm + mi * 16 + lr;
        af[mi][k2] = *(const short8*)(lsA[cur] + (row >> 3) * 512 + (row & 7) * 64 +
                                      (((k2 * 4 + lq) ^ (row & 7)) * 8));
      }
#pragma unroll
    for (int ni = 0; ni < FR; ni++)
#pragma unroll
      for (int k2 = 0; k2 < 2; k2++) {
        const int row = wn + ni * 16 + lr;
        bf[ni][k2] = *(const short8*)(lsB[cur] + (row >> 3) * 512 + (row & 7) * 64 +
                                      (((k2 * 4 + lq) ^ (row & 7)) * 8));
      }
#pragma unroll
    for (int k2 = 0; k2 < 2; k2++)
#pragma unroll
      for (int mi = 0; mi < FR; mi++)
#pragma unroll
        for (int ni = 0; ni < FR; ni++)
          acc[mi][ni] = __builtin_amdgcn_mfma_f32_16x16x32_bf16(
              af[mi][k2], bf[ni][k2], acc[mi][ni], 0, 0, 0);
    __syncthreads();
  }

#pragma unroll
  for (int mi = 0; mi < FR; mi++) {
#pragma unroll
    for (int r = 0; r < 4; r++) {
      const int row = bm + wm + mi * 16 + lq * 4 + r;
      float gfac = 0.f; const ushort* ggrow = nullptr;
      if (Gg) {
        gfac = __expf(-(float)(t0 + (row >> 11)) * 0.1f);   // adapt(t)
        ggrow = Gg + (size_t)(row & 2047) * 1024;
      }
#pragma unroll
      for (int ni = 0; ni < FR; ni++) {
        const int col = bn + wn + ni * 16 + lr;
        if (col < N) {
          float v = acc[mi][ni][r];
          if (bias) v += bias[col];
          if (Gg)  v += gfac * b2f(ggrow[col]);
          if (act == 1) v = fmaxf(v, 0.f);
          else if (act == 2) v = tanh_fast(v);
          else if (act == 3) v = sigf(v);
          if (Cf) Cf[(size_t)row * ldcf + col] = v;
          if (Cb) Cb[(size_t)row * ldcb + col] = f2b(v);
        }
      }
    }
  }
}

// ---------------------------------------------------------------------------
// 8-wave standalone BT=128 GEMM (extraction of the fused gemm path) for G[0].
// ---------------------------------------------------------------------------
__global__ __launch_bounds__(512, 2)
void k_gemm8(const ushort* __restrict__ gA, int glda,
             const ushort* __restrict__ gW,
             const float* __restrict__ gbias, const ushort* __restrict__ gGg,
             int gt0, ushort* __restrict__ gC, int gK) {
  __shared__ __align__(16) ushort lsA[2 * 8192];
  __shared__ __align__(16) ushort lsB[2 * 8192];
  const int tid = threadIdx.x;
  const int gb = blockIdx.x;             // 0..1279 = 8 x 160
  const int xcd = gb & 7, q = gb >> 3;
  const int byb = (q >> 4) * 16 + xcd * 2 + (q & 1);
  const int bxb = (q >> 1) & 7;
  const int bm = byb * 128, bn = bxb * 128;
  const int lane = tid & 63, wg = tid >> 6;     // wg in [0,8)
  const int lr = lane & 15, lq = lane >> 4;
  const int wm = (wg >> 2) * 64, wn = (wg & 3) * 32;
  const int srow = lane >> 3;
  const int scol = (((lane & 7) ^ srow)) * 8;

  f32x4 acc[4][2];
#pragma unroll
  for (int i = 0; i < 4; i++)
#pragma unroll
    for (int j = 0; j < 2; j++) acc[i][j] = (f32x4){0.f, 0.f, 0.f, 0.f};

#pragma unroll
  for (int c = 0; c < 2; c++) {
    const int ch = wg * 2 + c;
    const int r = ch * 8 + srow;
    gload16(gA + (size_t)(bm + r) * glda + scol, lsA + ch * 512);
    gload16(gW + (size_t)(bn + r) * glda + scol, lsB + ch * 512);
  }
  __syncthreads();

  const int T = gK >> 6;
  for (int t = 0; t < T; t++) {
    const int cur = t & 1;
    if (t + 1 < T) {
      const int kk = (t + 1) * 64;
#pragma unroll
      for (int c = 0; c < 2; c++) {
        const int ch = wg * 2 + c;
        const int r = ch * 8 + srow;
        gload16(gA + (size_t)(bm + r) * glda + kk + scol, lsA + (cur ^ 1) * 8192 + ch * 512);
        gload16(gW + (size_t)(bn + r) * glda + kk + scol, lsB + (cur ^ 1) * 8192 + ch * 512);
      }
    }
    {
      short8 af[4][2], bf[2][2];
#pragma unroll
      for (int mi = 0; mi < 4; mi++)
#pragma unroll
        for (int k2 = 0; k2 < 2; k2++) {
          const int row = wm + mi * 16 + lr;
          af[mi][k2] = *(const short8*)(lsA + cur * 8192 + (row >> 3) * 512 +
                                        (row & 7) * 64 + (((k2 * 4 + lq) ^ (row & 7)) * 8));
        }
#pragma unroll
      for (int ni = 0; ni < 2; ni++)
#pragma unroll
        for (int k2 = 0; k2 < 2; k2++) {
          const int row = wn + ni * 16 + lr;
          bf[ni][k2] = *(const short8*)(lsB + cur * 8192 + (row >> 3) * 512 +
                                        (row & 7) * 64 + (((k2 * 4 + lq) ^ (row & 7)) * 8));
        }
#pragma unroll
      for (int k2 = 0; k2 < 2; k2++)
#pragma unroll
        for (int mi = 0; mi < 4; mi++)
#pragma unroll
          for (int ni = 0; ni < 2; ni++)
            acc[mi][ni] = __builtin_amdgcn_mfma_f32_16x16x32_bf16(
                af[mi][k2], bf[ni][k2], acc[mi][ni], 0, 0, 0);
    }
    __syncthreads();
  }

#pragma unroll
  for (int mi = 0; mi < 4; mi++) {
#pragma unroll
    for (int r = 0; r < 4; r++) {
      const int row = bm + wm + mi * 16 + lq * 4 + r;
      float gfac = 0.f; const ushort* ggrow = nullptr;
      if (gGg) {
        gfac = __expf(-(float)(gt0 + (row >> 11)) * 0.1f);
        ggrow = gGg + (size_t)(row & 2047) * 1024;
      }
#pragma unroll
      for (int ni = 0; ni < 2; ni++) {
        const int col = bn + wn + ni * 16 + lr;
        float v = acc[mi][ni][r];
        if (gbias) v += gbias[col];
        if (gGg)  v += gfac * b2f(ggrow[col]);
        gC[(size_t)row * 1024 + col] = f2b(v);
      }
    }
  }
}

// ---------------------------------------------------------------------------
// FUSED kernel: blocks 0-127 = LSTM rec; blocks 128-1407 = next job's IH GEMM
// (8 waves, 64x32 sub-tile per wave).   [R24 form -- no copy branch]
// ---------------------------------------------------------------------------
__global__ __launch_bounds__(512, 2)
void k_fused(const ushort* __restrict__ IH, const ushort* __restrict__ Whh,
             float* __restrict__ hstate, float* __restrict__ cstate,
             ushort* __restrict__ Hout, float* __restrict__ Xout, int t0,
             const ushort* __restrict__ gA, int glda,
             const ushort* __restrict__ gW,
             const float* __restrict__ gbias, const ushort* __restrict__ gGg,
             int gt0, ushort* __restrict__ gC, int gK) {
  __shared__ __align__(16) ushort upool[37024];   // 74048 B
  const int tid = threadIdx.x;

  if (blockIdx.x < 128) {
    // ================= rec path =================
    ushort (*h_lds)[266] = (ushort(*)[266])upool;        // 4256 ushorts
    ushort* ih0 = upool + 4256;                          // 2 x 16384
    const int lane = tid & 63, w8 = tid >> 6;
    const int lr = lane & 15, lq = lane >> 4;
    const int b0 = blockIdx.x * 16;
    const int wcols = w8 * 32;

    short8 wres[2][8];
#pragma unroll
    for (int cg = 0; cg < 2; cg++) {
      const ushort* wp = Whh + (size_t)(wcols + cg * 16 + lr) * 256 + lq * 8;
#pragma unroll
      for (int kk = 0; kk < 8; kk++) wres[cg][kk] = *(const short8*)(wp + kk * 32);
    }

    float c_reg[2][4], h_reg[2][4];
#pragma unroll
    for (int cg = 0; cg < 2; cg++) {
      const int j = wcols + cg * 16 + lr;
#pragma unroll
      for (int r = 0; r < 4; r++) {
        const int s = lq * 4 + r;
        float hv = hstate[(size_t)(b0 + s) * 256 + j];
        c_reg[cg][r] = cstate[(size_t)(b0 + s) * 256 + j];
        h_reg[cg][r] = hv;
        h_lds[s][j] = f2b(hv);
      }
    }
    __syncthreads();

#define LOADB(buf, g, cg) { \
  const ushort* wp_ = Whh + (size_t)((g) * 256 + wcols + (cg) * 16 + lr) * 256 + lq * 8; \
  _Pragma("unroll") for (int kk = 0; kk < 8; kk++) (buf)[kk] = *(const short8*)(wp_ + kk * 32); }
#define MFMAB(buf, g, cg) { \
  _Pragma("unroll") for (int kk = 0; kk < 8; kk++) \
    acc[cg][g] = __builtin_amdgcn_mfma_f32_16x16x32_bf16(af[kk], (buf)[kk], acc[cg][g], 0, 0, 0); }
#define MFMAR(cg) { \
  _Pragma("unroll") for (int kk = 0; kk < 8; kk++) \
    acc[cg][0] = __builtin_amdgcn_mfma_f32_16x16x32_bf16(af[kk], wres[cg][kk], acc[cg][0], 0, 0, 0); }

    for (int blk = 0; blk < 10; blk += 2) {
      // burst-stage 2 steps of IH (2 x 32 KB) via global_load_lds
#pragma unroll
      for (int si = 0; si < 2; si++) {
        const ushort* src = IH + ((size_t)(blk + si) * 2048 + b0) * 1024;
#pragma unroll
        for (int u = 0; u < 4; u++) {
          const int bi = u * 8 + w8;
          gload16(src + (size_t)bi * 512 + lane * 8, ih0 + si * 16384 + bi * 512);
        }
      }
      __syncthreads();   // stage drained; h_lds from prev step visible

      for (int i2 = 0; i2 < 2; i2++) {
        const int tl = blk + i2;
        const ushort* ihc = ih0 + i2 * 16384;
        short8 af[8];
#pragma unroll
        for (int kk = 0; kk < 8; kk++)
          af[kk] = *(const short8*)(&h_lds[lr][kk * 32 + lq * 8]);
        __syncthreads();   // barrier-A

        f32x4 acc[2][4];
#pragma unroll
        for (int cg = 0; cg < 2; cg++)
#pragma unroll
          for (int g = 0; g < 4; g++) acc[cg][g] = (f32x4){0.f, 0.f, 0.f, 0.f};

        short8 wb0[8], wb1[8];
        LOADB(wb0, 1, 0);
        LOADB(wb1, 1, 1);
        MFMAR(0);
        MFMAR(1);
        MFMAB(wb0, 1, 0);
        LOADB(wb0, 2, 0);
        MFMAB(wb1, 1, 1);
        LOADB(wb1, 2, 1);
        MFMAB(wb0, 2, 0);
        LOADB(wb0, 3, 0);
        MFMAB(wb1, 2, 1);
        LOADB(wb1, 3, 1);
        MFMAB(wb0, 3, 0);
        MFMAB(wb1, 3, 1);

        const int t = t0 + tl;
#pragma unroll
        for (int cg = 0; cg < 2; cg++) {
          const int j = wcols + cg * 16 + lr;
#pragma unroll
          for (int r = 0; r < 4; r++) {
            const int s = lq * 4 + r;
            const float zi = acc[cg][0][r] + b2f(ihc[s * 1024 + j]);
            const float zf = acc[cg][1][r] + b2f(ihc[s * 1024 + 256 + j]);
            const float zg = acc[cg][2][r] + b2f(ihc[s * 1024 + 512 + j]);
            const float zo = acc[cg][3][r] + b2f(ihc[s * 1024 + 768 + j]);
            const float ig = sigf(zi), fg = sigf(zf), gg = tanh_fast(zg), og = sigf(zo);
            const float c = fg * c_reg[cg][r] + ig * gg;
            c_reg[cg][r] = c;
            const float h = og * tanh_fast(c);
            h_reg[cg][r] = h;
            h_lds[s][j] = f2b(h);
            if (Hout) Hout[((size_t)t * 2048 + b0 + s) * 256 + j] = f2b(h);
            if (Xout)
              __builtin_nontemporal_store(h, &Xout[((size_t)(b0 + s) * 50 + t) * 256 + j]);
          }
        }
        __syncthreads();   // barrier-B
      }
    }
#undef LOADB
#undef MFMAB
#undef MFMAR
#pragma unroll
    for (int cg = 0; cg < 2; cg++) {
      const int j = wcols + cg * 16 + lr;
#pragma unroll
      for (int r = 0; r < 4; r++) {
        const int s = lq * 4 + r;
        hstate[(size_t)(b0 + s) * 256 + j] = h_reg[cg][r];
        cstate[(size_t)(b0 + s) * 256 + j] = c_reg[cg][r];
      }
    }
  } else {
    // ============ gemm path: ALL 8 waves, 64x32 sub-tile per wave ============
    ushort* lsA = upool;            // 2 x 8192
    ushort* lsB = upool + 16384;    // 2 x 8192
    const int gb = blockIdx.x - 128;       // 0..1279 = 8 x 160
    const int xcd = gb & 7, q = gb >> 3;
    const int byb = (q >> 4) * 16 + xcd * 2 + (q & 1);
    const int bxb = (q >> 1) & 7;
    const int bm = byb * 128, bn = bxb * 128;
    const int lane = tid & 63, wg = tid >> 6;     // wg in [0,8)
    const int lr = lane & 15, lq = lane >> 4;
    const int wm = (wg >> 2) * 64, wn = (wg & 3) * 32;
    const int srow = lane >> 3;
    const int scol = (((lane & 7) ^ srow)) * 8;

    f32x4 acc[4][2];
#pragma unroll
    for (int i = 0; i < 4; i++)
#pragma unroll
      for (int j = 0; j < 2; j++) acc[i][j] = (f32x4){0.f, 0.f, 0.f, 0.f};

#pragma unroll
    for (int c = 0; c < 2; c++) {
      const int ch = wg * 2 + c;
      const int r = ch * 8 + srow;
      gload16(gA + (size_t)(bm + r) * glda + scol, lsA + ch * 512);
      gload16(gW + (size_t)(bn + r) * glda + scol, lsB + ch * 512);
    }
    __syncthreads();

    const int T = gK >> 6;
    for (int t = 0; t < T; t++) {
      const int cur = t & 1;
      if (t + 1 < T) {
        const int kk = (t + 1) * 64;
#pragma unroll
        for (int c = 0; c < 2; c++) {
          const int ch = wg * 2 + c;
          const int r = ch * 8 + srow;
          gload16(gA + (size_t)(bm + r) * glda + kk + scol, lsA + (cur ^ 1) * 8192 + ch * 512);
          gload16(gW + (size_t)(bn + r) * glda + kk + scol, lsB + (cur ^ 1) * 8192 + ch * 512);
        }
      }
      {
        short8 af[4][2], bf[2][2];
#pragma unroll
        for (int mi = 0; mi < 4; mi++)
#pragma unroll
          for (int k2 = 0; k2 < 2; k2++) {
            const int row = wm + mi * 16 + lr;
            af[mi][k2] = *(const short8*)(lsA + cur * 8192 + (row >> 3) * 512 +
                                          (row & 7) * 64 + (((k2 * 4 + lq) ^ (row & 7)) * 8));
          }
#pragma unroll
        for (int ni = 0; ni < 2; ni++)
#pragma unroll
          for (int k2 = 0; k2 < 2; k2++) {
            const int row = wn + ni * 16 + lr;
            bf[ni][k2] = *(const short8*)(lsB + cur * 8192 + (row >> 3) * 512 +
                                          (row & 7) * 64 + (((k2 * 4 + lq) ^ (row & 7)) * 8));
          }
#pragma unroll
        for (int k2 = 0; k2 < 2; k2++)
#pragma unroll
          for (int mi = 0; mi < 4; mi++)
#pragma unroll
            for (int ni = 0; ni < 2; ni++)
              acc[mi][ni] = __builtin_amdgcn_mfma_f32_16x16x32_bf16(
                  af[mi][k2], bf[ni][k2], acc[mi][ni], 0, 0, 0);
      }
      __syncthreads();
    }

    {
#pragma unroll
      for (int mi = 0; mi < 4; mi++) {
#pragma unroll
        for (int r = 0; r < 4; r++) {
          const int row = bm + wm + mi * 16 + lq * 4 + r;
          float gfac = 0.f; const ushort* ggrow = nullptr;
          if (gGg) {
            gfac = __expf(-(float)(gt0 + (row >> 11)) * 0.1f);
            ggrow = gGg + (size_t)(row & 2047) * 1024;
          }
#pragma unroll
          for (int ni = 0; ni < 2; ni++) {
            const int col = bn + wn + ni * 16 + lr;
            float v = acc[mi][ni][r];
            if (gbias) v += gbias[col];
            if (gGg)  v += gfac * b2f(ggrow[col]);
            gC[(size_t)row * 1024 + col] = f2b(v);
          }
        }
      }
    }
  }
}

// ---------------------------------------------------------------------------
// TAIL: blocks 0-5255 cffill; 5256-7303 valence; 7304-7311 entropy (8x256).
// ---------------------------------------------------------------------------
__global__ __launch_bounds__(256)
void k_tail(const float* __restrict__ hT, const ushort* __restrict__ recb,
            ushort* __restrict__ cf,
            const float* __restrict__ x, float* __restrict__ valout,
            const float* __restrict__ ar, const float* __restrict__ ai,
            float* __restrict__ partial) {
  __shared__ float red[256];
  const int tid = threadIdx.x;
  if (blockIdx.x < 5256) {
    long i = (long)blockIdx.x * 256 + tid;
    if (i < (long)2048 * 656) {
      long b = i / 656; int c = (int)(i % 656);
      cf[b * 704 + c] = (c < 256) ? f2b(hT[b * 256 + c]) : recb[b * 448 + (c - 256)];
    }
  } else if (blockIdx.x < 7304) {
    const float* p = x + (size_t)(blockIdx.x - 5256) * 12800;
    float a = 0.f;
    for (int i = tid; i < 12800; i += 256) a += tanh_fast(p[i]);
    red[tid] = a; __syncthreads();
    for (int s = 128; s > 0; s >>= 1) {
      if (tid < s) red[tid] += red[tid + s];
      __syncthreads();
    }
    if (tid == 0) valout[blockIdx.x - 5256] = red[0] * (1.f / 12800.f);
  } else {
    const int b = (blockIdx.x - 7304) * 256 + tid;
    float vr[16], vi[16];
#pragma unroll
    for (int i = 0; i < 16; i++) { vr[i] = ar[b * 16 + i]; vi[i] = ai[b * 16 + i]; }
    float m[64];
#pragma unroll
    for (int j = 0; j < 4; j++)
#pragma unroll
      for (int k = 0; k < 4; k++) {
        float re = 0.f, im = 0.f;
#pragma unroll
        for (int i = 0; i < 4; i++) {
          float xr = vr[i * 4 + j], xi = vi[i * 4 + j];
          float yr = vr[i * 4 + k], yi = vi[i * 4 + k];
          re += xr * yr + xi * yi;
          im += xi * yr - xr * yi;
        }
        m[j * 8 + k] = re;
        m[j * 8 + (k + 4)] = -im;
        m[(j + 4) * 8 + k] = im;
        m[(j + 4) * 8 + (k + 4)] = re;
      }
#pragma unroll 1
    for (int sweep = 0; sweep < 6; ++sweep) {
#pragma unroll
      for (int p = 0; p < 7; p++) {
#pragma unroll
        for (int q = p + 1; q < 8; q++) {
          const float apq = m[p * 8 + q];
          if (fabsf(apq) > 1e-28f) {
            const float app = m[p * 8 + p], aqq = m[q * 8 + q];
            const float tau = (aqq - app) / (2.f * apq);
            const float tt = (tau >= 0.f ? 1.f : -1.f) /
                             (fabsf(tau) + sqrtf(1.f + tau * tau));
            const float cc = 1.f / sqrtf(1.f + tt * tt);
            const float ssn = tt * cc;
#pragma unroll
            for (int k2 = 0; k2 < 8; k2++) {
              const float mp = m[p * 8 + k2], mq = m[q * 8 + k2];
              m[p * 8 + k2] = cc * mp - ssn * mq;
              m[q * 8 + k2] = ssn * mp + cc * mq;
            }
#pragma unroll
            for (int k2 = 0; k2 < 8; k2++) {
              const float mp = m[k2 * 8 + p], mq = m[k2 * 8 + q];
              m[k2 * 8 + p] = cc * mp - ssn * mq;
              m[k2 * 8 + q] = ssn * mp + cc * mq;
            }
          }
        }
      }
    }
    float e = 0.f;
#pragma unroll
    for (int k2 = 0; k2 < 8; k2++) {
      const float lam = fmaxf(m[k2 * 8 + k2], 1e-12f);
      e -= lam * logf(lam);
    }
    red[tid] = e; __syncthreads();
    for (int s = 128; s > 0; s >>= 1) {
      if (tid < s) red[tid] += red[tid + s];
      __syncthreads();
    }
    if (tid == 0) partial[blockIdx.x - 7304] = red[0];
  }
}

// block 0: consumer head mean; block 1: entropy finalize.
__global__ __launch_bounds__(256)
void k_consfin(const float* __restrict__ c3, const float* __restrict__ w4,
               const float* __restrict__ b4, float* __restrict__ outc,
               const float* __restrict__ partial, float* __restrict__ oute) {
  if (blockIdx.x == 0) {
    __shared__ float red[256];
    float accv = 0.f;
    for (int b = threadIdx.x; b < 2048; b += 256) {
      float d = b4[0];
#pragma unroll
      for (int k = 0; k < 64; k++) d += c3[(long)b * 64 + k] * w4[k];
      accv += sigf(d);
    }
    red[threadIdx.x] = accv; __syncthreads();
    for (int s = 128; s > 0; s >>= 1) {
      if (threadIdx.x < s) red[threadIdx.x] += red[threadIdx.x + s];
      __syncthreads();
    }
    if (threadIdx.x == 0) outc[0] = red[0] * (1.f / 2048.f);
  } else if (threadIdx.x == 0) {
    float s = 0.f;
    for (int i = 0; i < 8; i++) s += partial[i];
    oute[0] = s * (0.5f / 2048.f);
  }
}

// ---------------------------------------------------------------------------
extern "C" void kernel_launch(void* const* d_in, const int* in_sizes, int n_in,
                              void* d_out, int out_size, void* d_ws, size_t ws_size,
                              hipStream_t stream) {
  (void)in_sizes; (void)n_in; (void)out_size; (void)ws_size;
  const float* mf    = (const float*)d_in[0];
  const float* noise = (const float*)d_in[1];
  const float* ampr  = (const float*)d_in[2];
  const float* ampi  = (const float*)d_in[3];
  const float* Hre   = (const float*)d_in[4];
  const float* Him   = (const float*)d_in[5];
  const float* gpc   = (const float*)d_in[6];
  const float* bw1 = (const float*)d_in[7];  const float* bb1 = (const float*)d_in[8];
  const float* bw2 = (const float*)d_in[9];  const float* bb2 = (const float*)d_in[10];
  const float* bw3 = (const float*)d_in[11]; const float* bb3 = (const float*)d_in[12];
  const float* Wih[3] = {(const float*)d_in[13], (const float*)d_in[17], (const float*)d_in[21]};
  const float* Whh[3] = {(const float*)d_in[14], (const float*)d_in[18], (const float*)d_in[22]};
  const float* bih[3] = {(const float*)d_in[15], (const float*)d_in[19], (const float*)d_in[23]};
  const float* bhh[3] = {(const float*)d_in[16], (const float*)d_in[20], (const float*)d_in[24]};
  const float* cw1 = (const float*)d_in[25]; const float* cb1 = (const float*)d_in[26];
  const float* cw2 = (const float*)d_in[27]; const float* cb2 = (const float*)d_in[28];
  const float* cw3 = (const float*)d_in[29]; const float* cb3 = (const float*)d_in[30];
  const float* cw4 = (const float*)d_in[31]; const float* cb4 = (const float*)d_in[32];

  float* out = (float*)d_out;
  float* out_rec  = out;                    // [2048][400]
  float* out_seq  = out + 819200;           // [2048][50][256]
  float* out_val  = out + 27033600;         // [2048]
  float* out_cons = out + 27035648;
  float* out_ent  = out + 27035649;

  char* ws = (char*)d_ws;
  size_t off = 0;
  auto alloc = [&](size_t bytes) -> char* {
    char* p = ws + off; off += (bytes + 255) & ~(size_t)255; return p;
  };
  ushort* WB1   = (ushort*)alloc((size_t)256 * 576 * 2);
  ushort* WB2   = (ushort*)alloc((size_t)128 * 256 * 2);
  ushort* WB3   = (ushort*)alloc((size_t)512 * 128 * 2);
  ushort* WIH0  = (ushort*)alloc((size_t)1024 * 448 * 2);
  ushort* WIH0S = (ushort*)alloc((size_t)1024 * 448 * 2);
  ushort* WIH1  = (ushort*)alloc((size_t)1024 * 256 * 2);
  ushort* WIH2  = (ushort*)alloc((size_t)1024 * 256 * 2);
  ushort* WHH0  = (ushort*)alloc((size_t)1024 * 256 * 2);
  ushort* WHH1  = (ushort*)alloc((size_t)1024 * 256 * 2);
  ushort* WHH2  = (ushort*)alloc((size_t)1024 * 256 * 2);
  ushort* WC1   = (ushort*)alloc((size_t)512 * 704 * 2);
  ushort* WC2   = (ushort*)alloc((size_t)256 * 512 * 2);
  ushort* WC3   = (ushort*)alloc((size_t)128 * 256 * 2);
  float*  BSUM  = (float*)alloc((size_t)3 * 1024 * 4);
  ushort* BIO   = (ushort*)alloc((size_t)2048 * 576 * 2);
  ushort* H1B   = (ushort*)alloc((size_t)2048 * 256 * 2);
  ushort* H2B   = (ushort*)alloc((size_t)2048 * 128 * 2);
  ushort* RECB  = (ushort*)alloc((size_t)2048 * 448 * 2);
  ushort* GGB   = (ushort*)alloc((size_t)2048 * 1024 * 2);
  float*  AMPR  = (float*)alloc((size_t)2048 * 16 * 4);
  float*  AMPI  = (float*)alloc((size_t)2048 * 16 * 4);
  ushort* NCH0  = (ushort*)alloc((size_t)10 * 2048 * 448 * 2);
  ushort* NCH1  = (ushort*)alloc((size_t)10 * 2048 * 448 * 2);
  ushort* IHCA  = (ushort*)alloc((size_t)10 * 2048 * 1024 * 2);
  ushort* IHCB  = (ushort*)alloc((size_t)10 * 2048 * 1024 * 2);
  ushort* HBUF  = (ushort*)alloc((size_t)50 * 2048 * 256 * 2);
  float*  HST   = (float*)alloc((size_t)2048 * 256 * 4);
  float*  CST   = (float*)alloc((size_t)2048 * 256 * 4);   // adjacent to HST
  ushort* CFB   = (ushort*)alloc((size_t)2048 * 704 * 2);
  ushort* C1B   = (ushort*)alloc((size_t)2048 * 512 * 2);
  ushort* C2B   = (ushort*)alloc((size_t)2048 * 256 * 2);
  float*  C3F   = (float*)alloc((size_t)2048 * 64 * 4);
  float*  ENTP  = (float*)alloc((size_t)8 * 4);

  hipMemsetAsync(BIO,  0, (size_t)2048 * 576 * 2, stream);
  hipMemsetAsync(RECB, 0, (size_t)2048 * 448 * 2, stream);
  hipMemsetAsync(CFB,  0, (size_t)2048 * 704 * 2, stream);

  // ---- batched weight conversions (one launch) ----
  CJobs cj;
  auto J = [&](int k, const float* s, ushort* d, int sr, int dr, int sc, int dc,
               const float* sc_, int mode) {
    cj.j[k] = CJob{s, d, sc_, (long)dr * dc, sr, sc, dc, mode};
  };
  J(0,  bw1,    WB1,   256, 256, 528, 576, nullptr, 0);
  J(1,  bw2,    WB2,   128, 128, 256, 256, nullptr, 0);
  J(2,  bw3,    WB3,   400, 512, 128, 128, nullptr, 0);
  J(3,  Wih[0], WIH0,  1024, 1024, 400, 448, nullptr, 0);
  J(4,  Wih[0], WIH0S, 1024, 1024, 400, 448, gpc, 1);
  J(5,  Wih[1], WIH1,  1024, 1024, 256, 256, nullptr, 0);
  J(6,  Wih[2], WIH2,  1024, 1024, 256, 256, nullptr, 0);
  J(7,  Whh[0], WHH0,  1024, 1024, 256, 256, nullptr, 0);
  J(8,  Whh[1], WHH1,  1024, 1024, 256, 256, nullptr, 0);
  J(9,  Whh[2], WHH2,  1024, 1024, 256, 256, nullptr, 0);
  J(10, cw1,    WC1,   512, 512, 656, 704, nullptr, 0);
  J(11, cw2,    WC2,   256, 256, 512, 512, nullptr, 0);
  J(12, cw3,    WC3,   64, 128, 256, 256, nullptr, 0);
  hipLaunchKernelGGL(k_convbatch, dim3(13 * 256), dim3(256), 0, stream, cj);
  hipLaunchKernelGGL(k_vadd3, dim3(12), dim3(256), 0, stream,
                     bih[0], bhh[0], bih[1], bhh[1], bih[2], bhh[2], BSUM);

  // quantum || biofill || noise chunks 0,1 (one launch; copies at full occ.)
  hipLaunchKernelGGL(k_qb, dim3(10496), dim3(256), 0, stream,
                     ampr, ampi, Hre, Him, mf, BIO, AMPR, AMPI,
                     noise, NCH0, NCH1);

  auto gemm = [&](bool big, const ushort* A, int lda, const ushort* W, int ldw,
                  const float* bias, const ushort* Gg, int t0, float* Cf, int ldcf,
                  ushort* Cb, int ldcb, int M, int N, int K, int act) {
    if (big) {
      dim3 grid((N + 127) / 128, M / 128);
      const int swz = (grid.x == 8 && (grid.y & 15) == 0) ? 1 : 0;
      hipLaunchKernelGGL(k_gemm<128>, grid, dim3(256), 0, stream,
                         A, lda, W, ldw, bias, Gg, t0, Cf, ldcf, Cb, ldcb, N, K, act, swz);
    } else {
      dim3 grid((N + 63) / 64, M / 64);
      hipLaunchKernelGGL(k_gemm<64>, grid, dim3(256), 0, stream,
                         A, lda, W, ldw, bias, Gg, t0, Cf, ldcf, Cb, ldcb, N, K, act, 0);
    }
  };

  // receptor MLP
  gemm(false, BIO, 576, WB1, 576, bb1, nullptr, 0, nullptr, 0, H1B, 256, 2048, 256, 576, 1);
  gemm(false, H1B, 256, WB2, 256, bb2, nullptr, 0, nullptr, 0, H2B, 128, 2048, 128, 256, 2);
  gemm(false, H2B, 128, WB3, 128, bb3, nullptr, 0, out_rec, 400, RECB, 448, 2048, 400, 128, 3);
  // GGB = (receptor * sigmoid(gpc)) @ Wih0^T   (bf16)
  gemm(false, RECB, 448, WIH0S, 448, nullptr, nullptr, 0, nullptr, 0, GGB, 1024, 2048, 1024, 448, 0);

  // ---- fused LSTM pipeline: slot i = rec job i || gemm job i+1 ----
  const ushort* WHHl[3] = {WHH0, WHH1, WHH2};
  ushort* IHCbuf[2] = {IHCA, IHCB};
  ushort* NCHbuf[2] = {NCH0, NCH1};
  // G[0] standalone (8-wave); NCH0 chunk 0 staged by k_qb
  hipLaunchKernelGGL(k_gemm8, dim3(1280), dim3(512), 0, stream,
                     NCH0, 448, WIH0, BSUM, GGB, 0, IHCA, 448);

  for (int i = 0; i < 15; i++) {
    const int l = i / 5, c = i % 5;
    if (c == 0) hipMemsetAsync(HST, 0, (size_t)2048 * 256 * 4 * 2, stream);  // HST+CST
    const bool hg = (i + 1 < 15);
    const ushort* gA = nullptr; const ushort* gWp = nullptr;
    const float* gb_ = nullptr; const ushort* gGg = nullptr;
    int glda = 256, gK = 256, ggt0 = 0;
    if (hg) {
      const int l2 = (i + 1) / 5, c2 = (i + 1) % 5;
      if (l2 == 0) {
        // chunk c2 -> NCHbuf[c2&1]; chunks 0,1 staged by k_qb, 2,3,4 here.
        if (c2 >= 2)
          hipLaunchKernelGGL(k_noiseconv, dim3(8192), dim3(256), 0, stream,
                             noise, NCHbuf[c2 & 1], c2 * 10);
        gA = NCHbuf[c2 & 1]; glda = 448; gK = 448;
        gb_ = BSUM; gGg = GGB; ggt0 = c2 * 10; gWp = WIH0;
      } else {
        gA = HBUF + (size_t)(c2 * 10) * 2048 * 256; glda = 256; gK = 256;
        gb_ = BSUM + l2 * 1024; gGg = nullptr; ggt0 = 0;
        gWp = (l2 == 1 ? WIH1 : WIH2);
      }
    }
    dim3 grid(hg ? 1408 : 128);
    hipLaunchKernelGGL(k_fused, grid, dim3(512), 0, stream,
                       IHCbuf[i & 1], WHHl[l], HST, CST,
                       (l < 2 ? HBUF : (ushort*)nullptr),
                       (l == 2 ? out_seq : (float*)nullptr), c * 10,
                       gA, glda, gWp, gb_, gGg, ggt0, IHCbuf[(i + 1) & 1], gK);
  }

  // tail: cffill || valence || entropy (one launch), then consumer MLP
  hipLaunchKernelGGL(k_tail, dim3(7312), dim3(256), 0, stream,
                     HST, RECB, CFB, out_seq, out_val, AMPR, AMPI, ENTP);
  gemm(false, CFB, 704, WC1, 704, cb1, nullptr, 0, nullptr, 0, C1B, 512, 2048, 512, 704, 1);
  gemm(false, C1B, 512, WC2, 512, cb2, nullptr, 0, nullptr, 0, C2B, 256, 2048, 256, 512, 1);
  gemm(false, C2B, 256, WC3, 256, cb3, nullptr, 0, C3F, 64, nullptr, 0, 2048, 64, 256, 2);
  hipLaunchKernelGGL(k_consfin, dim3(2), dim3(256), 0, stream,
                     C3F, cw4, cb4, out_cons, ENTP, out_ent);
}

// Round 27
// 2485.830 us; speedup vs baseline: 1.0456x; 1.0162x over previous
//
#include <hip/hip_runtime.h>
#include <stdint.h>

// ---------------------------------------------------------------------------
// QuantumOlfactoryReceptor: full pipeline
// Round 27: base = R26 (2526us best). Single change: ALL 5 noise chunks staged
//  inside k_qb (hidden under latency-bound quantum, no-LDS full-occupancy
//  copies -- the pattern R25/R26 validated for chunks 0,1). One flat 5-chunk
//  NCH arena removes the buffer-lifetime constraint; the 3 remaining serial
//  k_noiseconv launches (~17us each) disappear.
// ---------------------------------------------------------------------------

using short8 = __attribute__((ext_vector_type(8))) short;
using f32x4  = __attribute__((ext_vector_type(4))) float;

#define DEV static __device__ __forceinline__

typedef const __attribute__((address_space(1))) void GV;
typedef __attribute__((address_space(3))) void LV;
DEV void gload16(const void* g, void* l) {
  __builtin_amdgcn_global_load_lds((GV*)g, (LV*)l, 16, 0, 0);
}

DEV ushort f2b(float x) {                       // f32 -> bf16 RNE
  union { float f; uint32_t u; } v; v.f = x;
  uint32_t r = v.u + 0x7FFFu + ((v.u >> 16) & 1u);
  return (ushort)(r >> 16);
}
DEV float b2f(ushort x) {
  union { uint32_t u; float f; } v; v.u = ((uint32_t)x) << 16; return v.f;
}
DEV float sigf(float x) { return 1.f / (1.f + __expf(-x)); }
DEV float tanh_fast(float x) {
  float xc = fminf(9.f, fmaxf(-9.f, x));
  float e = __expf(2.f * xc);
  return (e - 1.f) / (e + 1.f);
}

#define NCH_CHUNK 9175040L   // 10*2048*448 ushorts per chunk

// noise chunk copy body: 10 timesteps starting at t0 -> dst [10*2048][448] bf16
DEV void noisecopy(const float* __restrict__ noise, ushort* __restrict__ dst,
                   int t0, long start, long stride) {
  const long n = 10L * 2048 * 448;
  for (long idx = start; idx < n; idx += stride) {
    int r = (int)(idx % 448);
    long row = idx / 448;
    int b = (int)(row & 2047);
    int tl = (int)(row >> 11);
    ushort v = 0;
    if (r < 400)
      v = f2b(__builtin_nontemporal_load(&noise[((long)b * 50 + t0 + tl) * 400 + r]));
    dst[idx] = v;
  }
}

// ---------------------------------------------------------------------------
// batched fp32->bf16 weight conversion: 13 jobs, 256 blocks each.
// ---------------------------------------------------------------------------
struct CJob { const float* src; ushort* dst; const float* scale;
              long n; int sr, sc, dc, mode; };
struct CJobs { CJob j[13]; };

__global__ __launch_bounds__(256)
void k_convbatch(CJobs jobs) {
  const int job = blockIdx.x >> 8;
  const int blk = blockIdx.x & 255;
  const CJob J = jobs.j[job];
  for (long idx = (long)blk * 256 + threadIdx.x; idx < J.n; idx += 256L * 256) {
    int r = (int)(idx / J.dc), c = (int)(idx % J.dc);
    float v = 0.f;
    if (r < J.sr && c < J.sc) {
      v = J.src[(long)r * J.sc + c];
      if (J.mode == 1) v *= sigf(J.scale[c]);
    }
    J.dst[idx] = f2b(v);
  }
}

__global__ __launch_bounds__(256)
void k_vadd3(const float* a0, const float* b0, const float* a1, const float* b1,
             const float* a2, const float* b2, float* o) {
  const int job = blockIdx.x >> 2;
  const int i = (blockIdx.x & 3) * 256 + threadIdx.x;
  const float* a = (job == 0) ? a0 : (job == 1) ? a1 : a2;
  const float* b = (job == 0) ? b0 : (job == 1) ? b1 : b2;
  o[job * 1024 + i] = a[i] + b[i];
}

// ---------------------------------------------------------------------------
// FUSED quantum || biofill || noise chunks 0-4. Blocks 0-255: quantum.
// Blocks 256-2303: biofill. Blocks 2304-22783: chunk ci = (b-2304)/4096.
// (no LDS here -> copy branches run at full occupancy, hidden under quantum)
// ---------------------------------------------------------------------------
__global__ __launch_bounds__(256)
void k_qb(const float* __restrict__ ampr_in, const float* __restrict__ ampi_in,
          const float* __restrict__ Hre, const float* __restrict__ Him,
          const float* __restrict__ mf, ushort* __restrict__ bio,
          float* __restrict__ ampr_out, float* __restrict__ ampi_out,
          const float* __restrict__ noise, ushort* __restrict__ nch) {
  const int tid = threadIdx.x;
  if (blockIdx.x < 256) {
    const int gid = blockIdx.x * 256 + tid;
    const int b = gid >> 5;          // sample
    const int l32 = gid & 31;
    const int i = l32 & 15;          // row
    const int h = l32 >> 4;          // column half
    float hre[8], him[8];
#pragma unroll
    for (int jj = 0; jj < 8; jj++) {
      hre[jj] = Hre[i * 16 + h * 8 + jj];
      him[jj] = Him[i * 16 + h * 8 + jj];
    }
    const float mfi = mf[(long)b * 512 + i];
    float are = ampr_in[b * 16 + i], aim = ampi_in[b * 16 + i];
    float ss = are * are + aim * aim;
#pragma unroll
    for (int m = 1; m < 32; m <<= 1) ss += __shfl_xor(ss, m, 32);
    ss *= 0.5f;
    const float inv = 1.f / sqrtf(ss);
    are *= inv; aim *= inv;
#pragma unroll 1
    for (int st = 0; st < 100; ++st) {
      const float t = (float)st * 0.01f;
      const float fac = 1.f + t * mfi;
      const float dec = __expf(-t * 0.02f);   // exp(-t/50)
      float tre = are, tim = aim, rre = are, rim = aim;
#pragma unroll 1
      for (int k = 1; k <= 5; k++) {
        float w1r = 0.f, w1i = 0.f, w2r = 0.f, w2i = 0.f;
#pragma unroll
        for (int jj = 0; jj < 8; jj++) {
          const float vr = __shfl(tre, h * 8 + jj, 32);
          const float vi = __shfl(tim, h * 8 + jj, 32);
          w1r += hre[jj] * vr; w1i += hre[jj] * vi;
          w2r += him[jj] * vr; w2i += him[jj] * vi;
        }
        w1r += __shfl_xor(w1r, 16, 32);
        w1i += __shfl_xor(w1i, 16, 32);
        w2r += __shfl_xor(w2r, 16, 32);
        w2i += __shfl_xor(w2i, 16, 32);
        const float hr = w1r * fac - w2i;      // (Ht v)_re
        const float hi = w1i * fac + w2r;      // (Ht v)_im
        const float sk = 0.01f / (float)k;     // DT/k ; term *= -i*sk
        tre = sk * hi; tim = -sk * hr;
        rre += tre; rim += tim;
      }
      are = rre * dec; aim = rim * dec;
    }
    if (h == 0) {
      ampr_out[b * 16 + i] = are;
      ampi_out[b * 16 + i] = aim;
      bio[(long)b * 576 + i] = f2b(are * are + aim * aim);   // obs
    }
  } else if (blockIdx.x < 2304) {
    for (long i = (long)(blockIdx.x - 256) * 256 + tid; i < (long)2048 * 512;
         i += 2048L * 256) {
      long b = i >> 9, k = i & 511;
      bio[b * 576 + 16 + k] = f2b(mf[i]);
    }
  } else {
    const int cr = blockIdx.x - 2304;       // 0..20479
    const int ci = cr >> 12;                // chunk 0..4
    const int blk = cr & 4095;
    noisecopy(noise, nch + (long)ci * NCH_CHUNK, ci * 10,
              (long)blk * 256 + tid, 4096L * 256);
  }
}

// ---------------------------------------------------------------------------
// bf16 MFMA GEMM (standalone, 256 thr / 4 waves): used for small tiles.
// ---------------------------------------------------------------------------
template<int BT>
__global__ __launch_bounds__(256)
void k_gemm(const ushort* __restrict__ A, int lda,
            const ushort* __restrict__ W, int ldw,
            const float* __restrict__ bias,
            const ushort* __restrict__ Gg, int t0,
            float* __restrict__ Cf, int ldcf,
            ushort* __restrict__ Cb, int ldcb,
            int N, int K, int act, int swz) {
  constexpr int FR = BT / 32;
  constexpr int CH = BT / 32;
  __shared__ __align__(16) ushort lsA[2][BT * 64];
  __shared__ __align__(16) ushort lsB[2][BT * 64];
  const int tid = threadIdx.x;
  const int lane = tid & 63, w = tid >> 6;
  const int lr = lane & 15, lq = lane >> 4;
  const int wm = (w >> 1) * (BT / 2), wn = (w & 1) * (BT / 2);
  int bxb = blockIdx.x, byb = blockIdx.y;
  if (swz) {                      // b-aligned XCD remap (grid 8 x 16T)
    const int id = byb * gridDim.x + bxb;
    const int xcd = id & 7, q = id >> 3;
    byb = (q >> 4) * 16 + xcd * 2 + (q & 1);
    bxb = (q >> 1) & 7;
  }
  const int bm = byb * BT, bn = bxb * BT;
  const int srow = lane >> 3;
  const int scol = (((lane & 7) ^ srow)) * 8;

  auto stage = [&](int buf, int kk) {
#pragma unroll
    for (int c = 0; c < CH; c++) {
      const int ch = w * CH + c;
      const int r = ch * 8 + srow;
      gload16(A + (size_t)(bm + r) * lda + kk + scol, lsA[buf] + ch * 512);
      gload16(W + (size_t)(bn + r) * ldw + kk + scol, lsB[buf] + ch * 512);
    }
  };

  f32x4 acc[FR][FR];
#pragma unroll
  for (int i = 0; i < FR; i++)
#pragma unroll
    for (int j = 0; j < FR; j++) acc[i][j] = (f32x4){0.f, 0.f, 0.f, 0.f};

  stage(0, 0);
  __syncthreads();
  const int T = K >> 6;
  for (int t = 0; t < T; t++) {
    const int cur = t & 1;
    if (t + 1 < T) stage(cur ^ 1, (t + 1) * 64);
    short8 af[FR][2], bf[FR][2];
#pragma unroll
    for (int mi = 0; mi < FR; mi++)
#pragma unroll
      for (int k2 = 0; k2 < 2; k2++) {
        const int row = wm + mi * 16 + lr;
        af[mi][k2] = *(const short8*)(lsA[cur] + (row >> 3) * 512 + (row & 7) * 64 +
                                      (((k2 * 4 + lq) ^ (row & 7)) * 8));
      }
#pragma unroll
    for (int ni = 0; ni < FR; ni++)
#pragma unroll
      for (int k2 = 0; k2 < 2; k2++) {
        const int row = wn + ni * 16 + lr;
        bf[ni][k2] = *(const short8*)(lsB[cur] + (row >> 3) * 512 + (row & 7) * 64 +
                                      (((k2 * 4 + lq) ^ (row & 7)) * 8));
      }
#pragma unroll
    for (int k2 = 0; k2 < 2; k2++)
#pragma unroll
      for (int mi = 0; mi < FR; mi++)
#pragma unroll
        for (int ni = 0; ni < FR; ni++)
          acc[mi][ni] = __builtin_amdgcn_mfma_f32_16x16x32_bf16(
              af[mi][k2], bf[ni][k2], acc[mi][ni], 0, 0, 0);
    __syncthreads();
  }

#pragma unroll
  for (int mi = 0; mi < FR; mi++) {
#pragma unroll
    for (int r = 0; r < 4; r++) {
      const int row = bm + wm + mi * 16 + lq * 4 + r;
      float gfac = 0.f; const ushort* ggrow = nullptr;
      if (Gg) {
        gfac = __expf(-(float)(t0 + (row >> 11)) * 0.1f);   // adapt(t)
        ggrow = Gg + (size_t)(row & 2047) * 1024;
      }
#pragma unroll
      for (int ni = 0; ni < FR; ni++) {
        const int col = bn + wn + ni * 16 + lr;
        if (col < N) {
          float v = acc[mi][ni][r];
          if (bias) v += bias[col];
          if (Gg)  v += gfac * b2f(ggrow[col]);
          if (act == 1) v = fmaxf(v, 0.f);
          else if (act == 2) v = tanh_fast(v);
          else if (act == 3) v = sigf(v);
          if (Cf) Cf[(size_t)row * ldcf + col] = v;
          if (Cb) Cb[(size_t)row * ldcb + col] = f2b(v);
        }
      }
    }
  }
}

// ---------------------------------------------------------------------------
// 8-wave standalone BT=128 GEMM (extraction of the fused gemm path) for G[0].
// ---------------------------------------------------------------------------
__global__ __launch_bounds__(512, 2)
void k_gemm8(const ushort* __restrict__ gA, int glda,
             const ushort* __restrict__ gW,
             const float* __restrict__ gbias, const ushort* __restrict__ gGg,
             int gt0, ushort* __restrict__ gC, int gK) {
  __shared__ __align__(16) ushort lsA[2 * 8192];
  __shared__ __align__(16) ushort lsB[2 * 8192];
  const int tid = threadIdx.x;
  const int gb = blockIdx.x;             // 0..1279 = 8 x 160
  const int xcd = gb & 7, q = gb >> 3;
  const int byb = (q >> 4) * 16 + xcd * 2 + (q & 1);
  const int bxb = (q >> 1) & 7;
  const int bm = byb * 128, bn = bxb * 128;
  const int lane = tid & 63, wg = tid >> 6;     // wg in [0,8)
  const int lr = lane & 15, lq = lane >> 4;
  const int wm = (wg >> 2) * 64, wn = (wg & 3) * 32;
  const int srow = lane >> 3;
  const int scol = (((lane & 7) ^ srow)) * 8;

  f32x4 acc[4][2];
#pragma unroll
  for (int i = 0; i < 4; i++)
#pragma unroll
    for (int j = 0; j < 2; j++) acc[i][j] = (f32x4){0.f, 0.f, 0.f, 0.f};

#pragma unroll
  for (int c = 0; c < 2; c++) {
    const int ch = wg * 2 + c;
    const int r = ch * 8 + srow;
    gload16(gA + (size_t)(bm + r) * glda + scol, lsA + ch * 512);
    gload16(gW + (size_t)(bn + r) * glda + scol, lsB + ch * 512);
  }
  __syncthreads();

  const int T = gK >> 6;
  for (int t = 0; t < T; t++) {
    const int cur = t & 1;
    if (t + 1 < T) {
      const int kk = (t + 1) * 64;
#pragma unroll
      for (int c = 0; c < 2; c++) {
        const int ch = wg * 2 + c;
        const int r = ch * 8 + srow;
        gload16(gA + (size_t)(bm + r) * glda + kk + scol, lsA + (cur ^ 1) * 8192 + ch * 512);
        gload16(gW + (size_t)(bn + r) * glda + kk + scol, lsB + (cur ^ 1) * 8192 + ch * 512);
      }
    }
    {
      short8 af[4][2], bf[2][2];
#pragma unroll
      for (int mi = 0; mi < 4; mi++)
#pragma unroll
        for (int k2 = 0; k2 < 2; k2++) {
          const int row = wm + mi * 16 + lr;
          af[mi][k2] = *(const short8*)(lsA + cur * 8192 + (row >> 3) * 512 +
                                        (row & 7) * 64 + (((k2 * 4 + lq) ^ (row & 7)) * 8));
        }
#pragma unroll
      for (int ni = 0; ni < 2; ni++)
#pragma unroll
        for (int k2 = 0; k2 < 2; k2++) {
          const int row = wn + ni * 16 + lr;
          bf[ni][k2] = *(const short8*)(lsB + cur * 8192 + (row >> 3) * 512 +
                                        (row & 7) * 64 + (((k2 * 4 + lq) ^ (row & 7)) * 8));
        }
#pragma unroll
      for (int k2 = 0; k2 < 2; k2++)
#pragma unroll
        for (int mi = 0; mi < 4; mi++)
#pragma unroll
          for (int ni = 0; ni < 2; ni++)
            acc[mi][ni] = __builtin_amdgcn_mfma_f32_16x16x32_bf16(
                af[mi][k2], bf[ni][k2], acc[mi][ni], 0, 0, 0);
    }
    __syncthreads();
  }

#pragma unroll
  for (int mi = 0; mi < 4; mi++) {
#pragma unroll
    for (int r = 0; r < 4; r++) {
      const int row = bm + wm + mi * 16 + lq * 4 + r;
      float gfac = 0.f; const ushort* ggrow = nullptr;
      if (gGg) {
        gfac = __expf(-(float)(gt0 + (row >> 11)) * 0.1f);
        ggrow = gGg + (size_t)(row & 2047) * 1024;
      }
#pragma unroll
      for (int ni = 0; ni < 2; ni++) {
        const int col = bn + wn + ni * 16 + lr;
        float v = acc[mi][ni][r];
        if (gbias) v += gbias[col];
        if (gGg)  v += gfac * b2f(ggrow[col]);
        gC[(size_t)row * 1024 + col] = f2b(v);
      }
    }
  }
}

// ---------------------------------------------------------------------------
// FUSED kernel: blocks 0-127 = LSTM rec; blocks 128-1407 = next job's IH GEMM
// (8 waves, 64x32 sub-tile per wave).
// ---------------------------------------------------------------------------
__global__ __launch_bounds__(512, 2)
void k_fused(const ushort* __restrict__ IH, const ushort* __restrict__ Whh,
             float* __restrict__ hstate, float* __restrict__ cstate,
             ushort* __restrict__ Hout, float* __restrict__ Xout, int t0,
             const ushort* __restrict__ gA, int glda,
             const ushort* __restrict__ gW,
             const float* __restrict__ gbias, const ushort* __restrict__ gGg,
             int gt0, ushort* __restrict__ gC, int gK) {
  __shared__ __align__(16) ushort upool[37024];   // 74048 B
  const int tid = threadIdx.x;

  if (blockIdx.x < 128) {
    // ================= rec path =================
    ushort (*h_lds)[266] = (ushort(*)[266])upool;        // 4256 ushorts
    ushort* ih0 = upool + 4256;                          // 2 x 16384
    const int lane = tid & 63, w8 = tid >> 6;
    const int lr = lane & 15, lq = lane >> 4;
    const int b0 = blockIdx.x * 16;
    const int wcols = w8 * 32;

    short8 wres[2][8];
#pragma unroll
    for (int cg = 0; cg < 2; cg++) {
      const ushort* wp = Whh + (size_t)(wcols + cg * 16 + lr) * 256 + lq * 8;
#pragma unroll
      for (int kk = 0; kk < 8; kk++) wres[cg][kk] = *(const short8*)(wp + kk * 32);
    }

    float c_reg[2][4], h_reg[2][4];
#pragma unroll
    for (int cg = 0; cg < 2; cg++) {
      const int j = wcols + cg * 16 + lr;
#pragma unroll
      for (int r = 0; r < 4; r++) {
        const int s = lq * 4 + r;
        float hv = hstate[(size_t)(b0 + s) * 256 + j];
        c_reg[cg][r] = cstate[(size_t)(b0 + s) * 256 + j];
        h_reg[cg][r] = hv;
        h_lds[s][j] = f2b(hv);
      }
    }
    __syncthreads();

#define LOADB(buf, g, cg) { \
  const ushort* wp_ = Whh + (size_t)((g) * 256 + wcols + (cg) * 16 + lr) * 256 + lq * 8; \
  _Pragma("unroll") for (int kk = 0; kk < 8; kk++) (buf)[kk] = *(const short8*)(wp_ + kk * 32); }
#define MFMAB(buf, g, cg) { \
  _Pragma("unroll") for (int kk = 0; kk < 8; kk++) \
    acc[cg][g] = __builtin_amdgcn_mfma_f32_16x16x32_bf16(af[kk], (buf)[kk], acc[cg][g], 0, 0, 0); }
#define MFMAR(cg) { \
  _Pragma("unroll") for (int kk = 0; kk < 8; kk++) \
    acc[cg][0] = __builtin_amdgcn_mfma_f32_16x16x32_bf16(af[kk], wres[cg][kk], acc[cg][0], 0, 0, 0); }

    for (int blk = 0; blk < 10; blk += 2) {
      // burst-stage 2 steps of IH (2 x 32 KB) via global_load_lds
#pragma unroll
      for (int si = 0; si < 2; si++) {
        const ushort* src = IH + ((size_t)(blk + si) * 2048 + b0) * 1024;
#pragma unroll
        for (int u = 0; u < 4; u++) {
          const int bi = u * 8 + w8;
          gload16(src + (size_t)bi * 512 + lane * 8, ih0 + si * 16384 + bi * 512);
        }
      }
      __syncthreads();   // stage drained; h_lds from prev step visible

      for (int i2 = 0; i2 < 2; i2++) {
        const int tl = blk + i2;
        const ushort* ihc = ih0 + i2 * 16384;
        short8 af[8];
#pragma unroll
        for (int kk = 0; kk < 8; kk++)
          af[kk] = *(const short8*)(&h_lds[lr][kk * 32 + lq * 8]);
        __syncthreads();   // barrier-A

        f32x4 acc[2][4];
#pragma unroll
        for (int cg = 0; cg < 2; cg++)
#pragma unroll
          for (int g = 0; g < 4; g++) acc[cg][g] = (f32x4){0.f, 0.f, 0.f, 0.f};

        short8 wb0[8], wb1[8];
        LOADB(wb0, 1, 0);
        LOADB(wb1, 1, 1);
        MFMAR(0);
        MFMAR(1);
        MFMAB(wb0, 1, 0);
        LOADB(wb0, 2, 0);
        MFMAB(wb1, 1, 1);
        LOADB(wb1, 2, 1);
        MFMAB(wb0, 2, 0);
        LOADB(wb0, 3, 0);
        MFMAB(wb1, 2, 1);
        LOADB(wb1, 3, 1);
        MFMAB(wb0, 3, 0);
        MFMAB(wb1, 3, 1);

        const int t = t0 + tl;
#pragma unroll
        for (int cg = 0; cg < 2; cg++) {
          const int j = wcols + cg * 16 + lr;
#pragma unroll
          for (int r = 0; r < 4; r++) {
            const int s = lq * 4 + r;
            const float zi = acc[cg][0][r] + b2f(ihc[s * 1024 + j]);
            const float zf = acc[cg][1][r] + b2f(ihc[s * 1024 + 256 + j]);
            const float zg = acc[cg][2][r] + b2f(ihc[s * 1024 + 512 + j]);
            const float zo = acc[cg][3][r] + b2f(ihc[s * 1024 + 768 + j]);
            const float ig = sigf(zi), fg = sigf(zf), gg = tanh_fast(zg), og = sigf(zo);
            const float c = fg * c_reg[cg][r] + ig * gg;
            c_reg[cg][r] = c;
            const float h = og * tanh_fast(c);
            h_reg[cg][r] = h;
            h_lds[s][j] = f2b(h);
            if (Hout) Hout[((size_t)t * 2048 + b0 + s) * 256 + j] = f2b(h);
            if (Xout)
              __builtin_nontemporal_store(h, &Xout[((size_t)(b0 + s) * 50 + t) * 256 + j]);
          }
        }
        __syncthreads();   // barrier-B
      }
    }
#undef LOADB
#undef MFMAB
#undef MFMAR
#pragma unroll
    for (int cg = 0; cg < 2; cg++) {
      const int j = wcols + cg * 16 + lr;
#pragma unroll
      for (int r = 0; r < 4; r++) {
        const int s = lq * 4 + r;
        hstate[(size_t)(b0 + s) * 256 + j] = h_reg[cg][r];
        cstate[(size_t)(b0 + s) * 256 + j] = c_reg[cg][r];
      }
    }
  } else {
    // ============ gemm path: ALL 8 waves, 64x32 sub-tile per wave ============
    ushort* lsA = upool;            // 2 x 8192
    ushort* lsB = upool + 16384;    // 2 x 8192
    const int gb = blockIdx.x - 128;       // 0..1279 = 8 x 160
    const int xcd = gb & 7, q = gb >> 3;
    const int byb = (q >> 4) * 16 + xcd * 2 + (q & 1);
    const int bxb = (q >> 1) & 7;
    const int bm = byb * 128, bn = bxb * 128;
    const int lane = tid & 63, wg = tid >> 6;     // wg in [0,8)
    const int lr = lane & 15, lq = lane >> 4;
    const int wm = (wg >> 2) * 64, wn = (wg & 3) * 32;
    const int srow = lane >> 3;
    const int scol = (((lane & 7) ^ srow)) * 8;

    f32x4 acc[4][2];
#pragma unroll
    for (int i = 0; i < 4; i++)
#pragma unroll
      for (int j = 0; j < 2; j++) acc[i][j] = (f32x4){0.f, 0.f, 0.f, 0.f};

#pragma unroll
    for (int c = 0; c < 2; c++) {
      const int ch = wg * 2 + c;
      const int r = ch * 8 + srow;
      gload16(gA + (size_t)(bm + r) * glda + scol, lsA + ch * 512);
      gload16(gW + (size_t)(bn + r) * glda + scol, lsB + ch * 512);
    }
    __syncthreads();

    const int T = gK >> 6;
    for (int t = 0; t < T; t++) {
      const int cur = t & 1;
      if (t + 1 < T) {
        const int kk = (t + 1) * 64;
#pragma unroll
        for (int c = 0; c < 2; c++) {
          const int ch = wg * 2 + c;
          const int r = ch * 8 + srow;
          gload16(gA + (size_t)(bm + r) * glda + kk + scol, lsA + (cur ^ 1) * 8192 + ch * 512);
          gload16(gW + (size_t)(bn + r) * glda + kk + scol, lsB + (cur ^ 1) * 8192 + ch * 512);
        }
      }
      {
        short8 af[4][2], bf[2][2];
#pragma unroll
        for (int mi = 0; mi < 4; mi++)
#pragma unroll
          for (int k2 = 0; k2 < 2; k2++) {
            const int row = wm + mi * 16 + lr;
            af[mi][k2] = *(const short8*)(lsA + cur * 8192 + (row >> 3) * 512 +
                                          (row & 7) * 64 + (((k2 * 4 + lq) ^ (row & 7)) * 8));
          }
#pragma unroll
        for (int ni = 0; ni < 2; ni++)
#pragma unroll
          for (int k2 = 0; k2 < 2; k2++) {
            const int row = wn + ni * 16 + lr;
            bf[ni][k2] = *(const short8*)(lsB + cur * 8192 + (row >> 3) * 512 +
                                          (row & 7) * 64 + (((k2 * 4 + lq) ^ (row & 7)) * 8));
          }
#pragma unroll
        for (int k2 = 0; k2 < 2; k2++)
#pragma unroll
          for (int mi = 0; mi < 4; mi++)
#pragma unroll
            for (int ni = 0; ni < 2; ni++)
              acc[mi][ni] = __builtin_amdgcn_mfma_f32_16x16x32_bf16(
                  af[mi][k2], bf[ni][k2], acc[mi][ni], 0, 0, 0);
      }
      __syncthreads();
    }

    {
#pragma unroll
      for (int mi = 0; mi < 4; mi++) {
#pragma unroll
        for (int r = 0; r < 4; r++) {
          const int row = bm + wm + mi * 16 + lq * 4 + r;
          float gfac = 0.f; const ushort* ggrow = nullptr;
          if (gGg) {
            gfac = __expf(-(float)(gt0 + (row >> 11)) * 0.1f);
            ggrow = gGg + (size_t)(row & 2047) * 1024;
          }
#pragma unroll
          for (int ni = 0; ni < 2; ni++) {
            const int col = bn + wn + ni * 16 + lr;
            float v = acc[mi][ni][r];
            if (gbias) v += gbias[col];
            if (gGg)  v += gfac * b2f(ggrow[col]);
            gC[(size_t)row * 1024 + col] = f2b(v);
          }
        }
      }
    }
  }
}

// ---------------------------------------------------------------------------
// TAIL: blocks 0-5255 cffill; 5256-7303 valence; 7304-7311 entropy (8x256).
// ---------------------------------------------------------------------------
__global__ __launch_bounds__(256)
void k_tail(const float* __restrict__ hT, const ushort* __restrict__ recb,
            ushort* __restrict__ cf,
            const float* __restrict__ x, float* __restrict__ valout,
            const float* __restrict__ ar, const float* __restrict__ ai,
            float* __restrict__ partial) {
  __shared__ float red[256];
  const int tid = threadIdx.x;
  if (blockIdx.x < 5256) {
    long i = (long)blockIdx.x * 256 + tid;
    if (i < (long)2048 * 656) {
      long b = i / 656; int c = (int)(i % 656);
      cf[b * 704 + c] = (c < 256) ? f2b(hT[b * 256 + c]) : recb[b * 448 + (c - 256)];
    }
  } else if (blockIdx.x < 7304) {
    const float* p = x + (size_t)(blockIdx.x - 5256) * 12800;
    float a = 0.f;
    for (int i = tid; i < 12800; i += 256) a += tanh_fast(p[i]);
    red[tid] = a; __syncthreads();
    for (int s = 128; s > 0; s >>= 1) {
      if (tid < s) red[tid] += red[tid + s];
      __syncthreads();
    }
    if (tid == 0) valout[blockIdx.x - 5256] = red[0] * (1.f / 12800.f);
  } else {
    const int b = (blockIdx.x - 7304) * 256 + tid;
    float vr[16], vi[16];
#pragma unroll
    for (int i = 0; i < 16; i++) { vr[i] = ar[b * 16 + i]; vi[i] = ai[b * 16 + i]; }
    float m[64];
#pragma unroll
    for (int j = 0; j < 4; j++)
#pragma unroll
      for (int k = 0; k < 4; k++) {
        float re = 0.f, im = 0.f;
#pragma unroll
        for (int i = 0; i < 4; i++) {
          float xr = vr[i * 4 + j], xi = vi[i * 4 + j];
          float yr = vr[i * 4 + k], yi = vi[i * 4 + k];
          re += xr * yr + xi * yi;
          im += xi * yr - xr * yi;
        }
        m[j * 8 + k] = re;
        m[j * 8 + (k + 4)] = -im;
        m[(j + 4) * 8 + k] = im;
        m[(j + 4) * 8 + (k + 4)] = re;
      }
#pragma unroll 1
    for (int sweep = 0; sweep < 6; ++sweep) {
#pragma unroll
      for (int p = 0; p < 7; p++) {
#pragma unroll
        for (int q = p + 1; q < 8; q++) {
          const float apq = m[p * 8 + q];
          if (fabsf(apq) > 1e-28f) {
            const float app = m[p * 8 + p], aqq = m[q * 8 + q];
            const float tau = (aqq - app) / (2.f * apq);
            const float tt = (tau >= 0.f ? 1.f : -1.f) /
                             (fabsf(tau) + sqrtf(1.f + tau * tau));
            const float cc = 1.f / sqrtf(1.f + tt * tt);
            const float ssn = tt * cc;
#pragma unroll
            for (int k2 = 0; k2 < 8; k2++) {
              const float mp = m[p * 8 + k2], mq = m[q * 8 + k2];
              m[p * 8 + k2] = cc * mp - ssn * mq;
              m[q * 8 + k2] = ssn * mp + cc * mq;
            }
#pragma unroll
            for (int k2 = 0; k2 < 8; k2++) {
              const float mp = m[k2 * 8 + p], mq = m[k2 * 8 + q];
              m[k2 * 8 + p] = cc * mp - ssn * mq;
              m[k2 * 8 + q] = ssn * mp + cc * mq;
            }
          }
        }
      }
    }
    float e = 0.f;
#pragma unroll
    for (int k2 = 0; k2 < 8; k2++) {
      const float lam = fmaxf(m[k2 * 8 + k2], 1e-12f);
      e -= lam * logf(lam);
    }
    red[tid] = e; __syncthreads();
    for (int s = 128; s > 0; s >>= 1) {
      if (tid < s) red[tid] += red[tid + s];
      __syncthreads();
    }
    if (tid == 0) partial[blockIdx.x - 7304] = red[0];
  }
}

// block 0: consumer head mean; block 1: entropy finalize.
__global__ __launch_bounds__(256)
void k_consfin(const float* __restrict__ c3, const float* __restrict__ w4,
               const float* __restrict__ b4, float* __restrict__ outc,
               const float* __restrict__ partial, float* __restrict__ oute) {
  if (blockIdx.x == 0) {
    __shared__ float red[256];
    float accv = 0.f;
    for (int b = threadIdx.x; b < 2048; b += 256) {
      float d = b4[0];
#pragma unroll
      for (int k = 0; k < 64; k++) d += c3[(long)b * 64 + k] * w4[k];
      accv += sigf(d);
    }
    red[threadIdx.x] = accv; __syncthreads();
    for (int s = 128; s > 0; s >>= 1) {
      if (threadIdx.x < s) red[threadIdx.x] += red[threadIdx.x + s];
      __syncthreads();
    }
    if (threadIdx.x == 0) outc[0] = red[0] * (1.f / 2048.f);
  } else if (threadIdx.x == 0) {
    float s = 0.f;
    for (int i = 0; i < 8; i++) s += partial[i];
    oute[0] = s * (0.5f / 2048.f);
  }
}

// ---------------------------------------------------------------------------
extern "C" void kernel_launch(void* const* d_in, const int* in_sizes, int n_in,
                              void* d_out, int out_size, void* d_ws, size_t ws_size,
                              hipStream_t stream) {
  (void)in_sizes; (void)n_in; (void)out_size; (void)ws_size;
  const float* mf    = (const float*)d_in[0];
  const float* noise = (const float*)d_in[1];
  const float* ampr  = (const float*)d_in[2];
  const float* ampi  = (const float*)d_in[3];
  const float* Hre   = (const float*)d_in[4];
  const float* Him   = (const float*)d_in[5];
  const float* gpc   = (const float*)d_in[6];
  const float* bw1 = (const float*)d_in[7];  const float* bb1 = (const float*)d_in[8];
  const float* bw2 = (const float*)d_in[9];  const float* bb2 = (const float*)d_in[10];
  const float* bw3 = (const float*)d_in[11]; const float* bb3 = (const float*)d_in[12];
  const float* Wih[3] = {(const float*)d_in[13], (const float*)d_in[17], (const float*)d_in[21]};
  const float* Whh[3] = {(const float*)d_in[14], (const float*)d_in[18], (const float*)d_in[22]};
  const float* bih[3] = {(const float*)d_in[15], (const float*)d_in[19], (const float*)d_in[23]};
  const float* bhh[3] = {(const float*)d_in[16], (const float*)d_in[20], (const float*)d_in[24]};
  const float* cw1 = (const float*)d_in[25]; const float* cb1 = (const float*)d_in[26];
  const float* cw2 = (const float*)d_in[27]; const float* cb2 = (const float*)d_in[28];
  const float* cw3 = (const float*)d_in[29]; const float* cb3 = (const float*)d_in[30];
  const float* cw4 = (const float*)d_in[31]; const float* cb4 = (const float*)d_in[32];

  float* out = (float*)d_out;
  float* out_rec  = out;                    // [2048][400]
  float* out_seq  = out + 819200;           // [2048][50][256]
  float* out_val  = out + 27033600;         // [2048]
  float* out_cons = out + 27035648;
  float* out_ent  = out + 27035649;

  char* ws = (char*)d_ws;
  size_t off = 0;
  auto alloc = [&](size_t bytes) -> char* {
    char* p = ws + off; off += (bytes + 255) & ~(size_t)255; return p;
  };
  ushort* WB1   = (ushort*)alloc((size_t)256 * 576 * 2);
  ushort* WB2   = (ushort*)alloc((size_t)128 * 256 * 2);
  ushort* WB3   = (ushort*)alloc((size_t)512 * 128 * 2);
  ushort* WIH0  = (ushort*)alloc((size_t)1024 * 448 * 2);
  ushort* WIH0S = (ushort*)alloc((size_t)1024 * 448 * 2);
  ushort* WIH1  = (ushort*)alloc((size_t)1024 * 256 * 2);
  ushort* WIH2  = (ushort*)alloc((size_t)1024 * 256 * 2);
  ushort* WHH0  = (ushort*)alloc((size_t)1024 * 256 * 2);
  ushort* WHH1  = (ushort*)alloc((size_t)1024 * 256 * 2);
  ushort* WHH2  = (ushort*)alloc((size_t)1024 * 256 * 2);
  ushort* WC1   = (ushort*)alloc((size_t)512 * 704 * 2);
  ushort* WC2   = (ushort*)alloc((size_t)256 * 512 * 2);
  ushort* WC3   = (ushort*)alloc((size_t)128 * 256 * 2);
  float*  BSUM  = (float*)alloc((size_t)3 * 1024 * 4);
  ushort* BIO   = (ushort*)alloc((size_t)2048 * 576 * 2);
  ushort* H1B   = (ushort*)alloc((size_t)2048 * 256 * 2);
  ushort* H2B   = (ushort*)alloc((size_t)2048 * 128 * 2);
  ushort* RECB  = (ushort*)alloc((size_t)2048 * 448 * 2);
  ushort* GGB   = (ushort*)alloc((size_t)2048 * 1024 * 2);
  float*  AMPR  = (float*)alloc((size_t)2048 * 16 * 4);
  float*  AMPI  = (float*)alloc((size_t)2048 * 16 * 4);
  ushort* NCHC  = (ushort*)alloc((size_t)5 * NCH_CHUNK * 2);   // 5-chunk arena
  ushort* IHCA  = (ushort*)alloc((size_t)10 * 2048 * 1024 * 2);
  ushort* IHCB  = (ushort*)alloc((size_t)10 * 2048 * 1024 * 2);
  ushort* HBUF  = (ushort*)alloc((size_t)50 * 2048 * 256 * 2);
  float*  HST   = (float*)alloc((size_t)2048 * 256 * 4);
  float*  CST   = (float*)alloc((size_t)2048 * 256 * 4);   // adjacent to HST
  ushort* CFB   = (ushort*)alloc((size_t)2048 * 704 * 2);
  ushort* C1B   = (ushort*)alloc((size_t)2048 * 512 * 2);
  ushort* C2B   = (ushort*)alloc((size_t)2048 * 256 * 2);
  float*  C3F   = (float*)alloc((size_t)2048 * 64 * 4);
  float*  ENTP  = (float*)alloc((size_t)8 * 4);

  hipMemsetAsync(BIO,  0, (size_t)2048 * 576 * 2, stream);
  hipMemsetAsync(RECB, 0, (size_t)2048 * 448 * 2, stream);
  hipMemsetAsync(CFB,  0, (size_t)2048 * 704 * 2, stream);

  // ---- batched weight conversions (one launch) ----
  CJobs cj;
  auto J = [&](int k, const float* s, ushort* d, int sr, int dr, int sc, int dc,
               const float* sc_, int mode) {
    cj.j[k] = CJob{s, d, sc_, (long)dr * dc, sr, sc, dc, mode};
  };
  J(0,  bw1,    WB1,   256, 256, 528, 576, nullptr, 0);
  J(1,  bw2,    WB2,   128, 128, 256, 256, nullptr, 0);
  J(2,  bw3,    WB3,   400, 512, 128, 128, nullptr, 0);
  J(3,  Wih[0], WIH0,  1024, 1024, 400, 448, nullptr, 0);
  J(4,  Wih[0], WIH0S, 1024, 1024, 400, 448, gpc, 1);
  J(5,  Wih[1], WIH1,  1024, 1024, 256, 256, nullptr, 0);
  J(6,  Wih[2], WIH2,  1024, 1024, 256, 256, nullptr, 0);
  J(7,  Whh[0], WHH0,  1024, 1024, 256, 256, nullptr, 0);
  J(8,  Whh[1], WHH1,  1024, 1024, 256, 256, nullptr, 0);
  J(9,  Whh[2], WHH2,  1024, 1024, 256, 256, nullptr, 0);
  J(10, cw1,    WC1,   512, 512, 656, 704, nullptr, 0);
  J(11, cw2,    WC2,   256, 256, 512, 512, nullptr, 0);
  J(12, cw3,    WC3,   64, 128, 256, 256, nullptr, 0);
  hipLaunchKernelGGL(k_convbatch, dim3(13 * 256), dim3(256), 0, stream, cj);
  hipLaunchKernelGGL(k_vadd3, dim3(12), dim3(256), 0, stream,
                     bih[0], bhh[0], bih[1], bhh[1], bih[2], bhh[2], BSUM);

  // quantum || biofill || noise chunks 0-4 (one launch; copies at full occ.)
  hipLaunchKernelGGL(k_qb, dim3(22784), dim3(256), 0, stream,
                     ampr, ampi, Hre, Him, mf, BIO, AMPR, AMPI, noise, NCHC);

  auto gemm = [&](bool big, const ushort* A, int lda, const ushort* W, int ldw,
                  const float* bias, const ushort* Gg, int t0, float* Cf, int ldcf,
                  ushort* Cb, int ldcb, int M, int N, int K, int act) {
    if (big) {
      dim3 grid((N + 127) / 128, M / 128);
      const int swz = (grid.x == 8 && (grid.y & 15) == 0) ? 1 : 0;
      hipLaunchKernelGGL(k_gemm<128>, grid, dim3(256), 0, stream,
                         A, lda, W, ldw, bias, Gg, t0, Cf, ldcf, Cb, ldcb, N, K, act, swz);
    } else {
      dim3 grid((N + 63) / 64, M / 64);
      hipLaunchKernelGGL(k_gemm<64>, grid, dim3(256), 0, stream,
                         A, lda, W, ldw, bias, Gg, t0, Cf, ldcf, Cb, ldcb, N, K, act, 0);
    }
  };

  // receptor MLP
  gemm(false, BIO, 576, WB1, 576, bb1, nullptr, 0, nullptr, 0, H1B, 256, 2048, 256, 576, 1);
  gemm(false, H1B, 256, WB2, 256, bb2, nullptr, 0, nullptr, 0, H2B, 128, 2048, 128, 256, 2);
  gemm(false, H2B, 128, WB3, 128, bb3, nullptr, 0, out_rec, 400, RECB, 448, 2048, 400, 128, 3);
  // GGB = (receptor * sigmoid(gpc)) @ Wih0^T   (bf16)
  gemm(false, RECB, 448, WIH0S, 448, nullptr, nullptr, 0, nullptr, 0, GGB, 1024, 2048, 1024, 448, 0);

  // ---- fused LSTM pipeline: slot i = rec job i || gemm job i+1 ----
  const ushort* WHHl[3] = {WHH0, WHH1, WHH2};
  ushort* IHCbuf[2] = {IHCA, IHCB};
  // G[0] standalone (8-wave); chunk 0 staged by k_qb
  hipLaunchKernelGGL(k_gemm8, dim3(1280), dim3(512), 0, stream,
                     NCHC, 448, WIH0, BSUM, GGB, 0, IHCA, 448);

  for (int i = 0; i < 15; i++) {
    const int l = i / 5, c = i % 5;
    if (c == 0) hipMemsetAsync(HST, 0, (size_t)2048 * 256 * 4 * 2, stream);  // HST+CST
    const bool hg = (i + 1 < 15);
    const ushort* gA = nullptr; const ushort* gWp = nullptr;
    const float* gb_ = nullptr; const ushort* gGg = nullptr;
    int glda = 256, gK = 256, ggt0 = 0;
    if (hg) {
      const int l2 = (i + 1) / 5, c2 = (i + 1) % 5;
      if (l2 == 0) {
        gA = NCHC + (size_t)c2 * NCH_CHUNK; glda = 448; gK = 448;
        gb_ = BSUM; gGg = GGB; ggt0 = c2 * 10; gWp = WIH0;
      } else {
        gA = HBUF + (size_t)(c2 * 10) * 2048 * 256; glda = 256; gK = 256;
        gb_ = BSUM + l2 * 1024; gGg = nullptr; ggt0 = 0;
        gWp = (l2 == 1 ? WIH1 : WIH2);
      }
    }
    dim3 grid(hg ? 1408 : 128);
    hipLaunchKernelGGL(k_fused, grid, dim3(512), 0, stream,
                       IHCbuf[i & 1], WHHl[l], HST, CST,
                       (l < 2 ? HBUF : (ushort*)nullptr),
                       (l == 2 ? out_seq : (float*)nullptr), c * 10,
                       gA, glda, gWp, gb_, gGg, ggt0, IHCbuf[(i + 1) & 1], gK);
  }

  // tail: cffill || valence || entropy (one launch), then consumer MLP
  hipLaunchKernelGGL(k_tail, dim3(7312), dim3(256), 0, stream,
                     HST, RECB, CFB, out_seq, out_val, AMPR, AMPI, ENTP);
  gemm(false, CFB, 704, WC1, 704, cb1, nullptr, 0, nullptr, 0, C1B, 512, 2048, 512, 704, 1);
  gemm(false, C1B, 512, WC2, 512, cb2, nullptr, 0, nullptr, 0, C2B, 256, 2048, 256, 512, 1);
  gemm(false, C2B, 256, WC3, 256, cb3, nullptr, 0, C3F, 64, nullptr, 0, 2048, 64, 256, 2);
  hipLaunchKernelGGL(k_consfin, dim3(2), dim3(256), 0, stream,
                     C3F, cw4, cb4, out_cons, ENTP, out_ent);
}